// Round 1
// baseline (368.990 us; speedup 1.0000x reference)
//
#include <hip/hip_runtime.h>

#define NTRAIN 32768
#define NBDY   4096

__device__ __forceinline__ float fast_tanh(float z) {
    float e = __expf(2.0f * z);
    return 1.0f - 2.0f / (e + 1.0f);
}

// ---------------------------------------------------------------------------
// Physics kernel: 256 threads/block, 16 points/block, 2048 blocks.
// 5 AD streams per point: [0]=value [1]=d/dx [2]=d/dy [3]=d2/dx2 [4]=d2/dy2
// LDS state A[unit][p*5+s], row stride 81 floats.
// Thread (p = t>>4, c = t&15): GEMM tile = point p, 5 streams, cols c*8..c*8+7
// ---------------------------------------------------------------------------
__global__ __launch_bounds__(256) void physics_kernel(
    const float* __restrict__ xt,
    const float* __restrict__ W0, const float* __restrict__ b0,
    const float* __restrict__ W1, const float* __restrict__ b1,
    const float* __restrict__ W2, const float* __restrict__ b2,
    const float* __restrict__ W3, const float* __restrict__ b3,
    const float* __restrict__ W4, const float* __restrict__ b4,
    const float* __restrict__ V0, const float* __restrict__ c0,
    const float* __restrict__ V1, const float* __restrict__ c1,
    const float* __restrict__ V2, const float* __restrict__ c2,
    float* __restrict__ out)
{
    __shared__ float A[128 * 81];     // main MLP state, 5 streams
    __shared__ float MU[64 * 17];     // mu MLP hidden state
    __shared__ float OUTF[5 * 16 * 4];// final outputs: [stream][point][4]
    __shared__ float MUV[16];         // mu per point

    const int t = threadIdx.x;
    const int p = t >> 4;   // point 0..15
    const int c = t & 15;   // col group 0..15

    const int ptIdx = blockIdx.x * 16 + p;
    const float x = xt[ptIdx * 2 + 0];
    const float y = xt[ptIdx * 2 + 1];

    // ---------------- mu MLP (forward only) ----------------
    // layer 1: 2 -> 64, each thread does 4 units for its point
    {
        #pragma unroll
        for (int i = 0; i < 4; i++) {
            int u = c * 4 + i;
            float z = x * V0[u] + y * V0[64 + u] + c0[u];
            MU[u * 17 + p] = fast_tanh(z);
        }
    }
    __syncthreads();
    // layer 2: 64 -> 64
    {
        float acc[4];
        #pragma unroll
        for (int i = 0; i < 4; i++) acc[i] = c1[c * 4 + i];
        #pragma unroll 4
        for (int k = 0; k < 64; k++) {
            float a = MU[k * 17 + p];
            float4 w = *(const float4*)(V1 + k * 64 + c * 4);
            acc[0] += a * w.x; acc[1] += a * w.y;
            acc[2] += a * w.z; acc[3] += a * w.w;
        }
        __syncthreads();
        #pragma unroll
        for (int i = 0; i < 4; i++) MU[(c * 4 + i) * 17 + p] = fast_tanh(acc[i]);
    }
    __syncthreads();
    // layer 3: 64 -> 1, mu = 0.01*s^2
    {
        float partial = 0.f;
        #pragma unroll
        for (int i = 0; i < 4; i++) {
            int k = c * 4 + i;
            partial += MU[k * 17 + p] * V2[k];
        }
        partial += __shfl_down(partial, 8);
        partial += __shfl_down(partial, 4);
        partial += __shfl_down(partial, 2);
        partial += __shfl_down(partial, 1);
        if (c == 0) {
            float s = partial + c2[0];
            MUV[p] = 0.01f * s * s;
        }
    }
    __syncthreads();

    // ---------------- main MLP layer 0: 2 -> 128, 5 streams ----------------
    {
        #pragma unroll
        for (int j = 0; j < 8; j++) {
            int u = c * 8 + j;
            float w0 = W0[u], w1 = W0[128 + u];
            float zv = x * w0 + y * w1 + b0[u];
            float tt = fast_tanh(zv);
            float s2 = 1.f - tt * tt;
            float m2 = -2.f * tt * s2;
            float* base = &A[u * 81 + p * 5];
            base[0] = tt;
            base[1] = s2 * w0;
            base[2] = s2 * w1;
            base[3] = m2 * w0 * w0;   // z_xx = 0 at layer 0
            base[4] = m2 * w1 * w1;
        }
    }
    __syncthreads();

    // ---------------- hidden layers 1..3: 128 -> 128, 5 streams ------------
    const float* Ws[3] = { W1, W2, W3 };
    const float* Bs[3] = { b1, b2, b3 };
    for (int l = 0; l < 3; l++) {
        const float* __restrict__ W = Ws[l];
        float acc0[8], acc1[8], acc2[8], acc3[8], acc4[8];
        #pragma unroll
        for (int j = 0; j < 8; j++) {
            acc0[j] = Bs[l][c * 8 + j];
            acc1[j] = 0.f; acc2[j] = 0.f; acc3[j] = 0.f; acc4[j] = 0.f;
        }
        const float* Abase = &A[p * 5];
        #pragma unroll 4
        for (int k = 0; k < 128; k++) {
            float a0 = Abase[k * 81 + 0];
            float a1 = Abase[k * 81 + 1];
            float a2 = Abase[k * 81 + 2];
            float a3 = Abase[k * 81 + 3];
            float a4 = Abase[k * 81 + 4];
            float4 wA = *(const float4*)(W + k * 128 + c * 8);
            float4 wB = *(const float4*)(W + k * 128 + c * 8 + 4);
            float w[8] = { wA.x, wA.y, wA.z, wA.w, wB.x, wB.y, wB.z, wB.w };
            #pragma unroll
            for (int j = 0; j < 8; j++) {
                acc0[j] += a0 * w[j];
                acc1[j] += a1 * w[j];
                acc2[j] += a2 * w[j];
                acc3[j] += a3 * w[j];
                acc4[j] += a4 * w[j];
            }
        }
        __syncthreads();
        #pragma unroll
        for (int j = 0; j < 8; j++) {
            float tt = fast_tanh(acc0[j]);
            float s2 = 1.f - tt * tt;
            float m2 = -2.f * tt * s2;
            float gx = acc1[j], gy = acc2[j];
            float* base = &A[(c * 8 + j) * 81 + p * 5];
            base[0] = tt;
            base[1] = s2 * gx;
            base[2] = s2 * gy;
            base[3] = s2 * acc3[j] + m2 * gx * gx;
            base[4] = s2 * acc4[j] + m2 * gy * gy;
        }
        __syncthreads();
    }

    // ---------------- layer 4: 128 -> 4 (linear), all 5 streams ------------
    if (t < 80) {
        int s  = t / 16;
        int pp = t % 16;
        float a0 = 0.f, a1 = 0.f, a2 = 0.f, a3 = 0.f;
        if (s == 0) { a0 = b4[0]; a1 = b4[1]; a2 = b4[2]; a3 = b4[3]; }
        const float* Abase = &A[pp * 5 + s];
        #pragma unroll 4
        for (int k = 0; k < 128; k++) {
            float a = Abase[k * 81];
            float4 w = *(const float4*)(W4 + k * 4);
            a0 += a * w.x; a1 += a * w.y; a2 += a * w.z; a3 += a * w.w;
        }
        float* o = &OUTF[(s * 16 + pp) * 4];
        o[0] = a0; o[1] = a1; o[2] = a2; o[3] = a3;
    }
    __syncthreads();

    // ---------------- per-point residual + reduction -----------------------
    float contrib = 0.f;
    if (t < 16) {
        const int pp = t;
        const float* V  = &OUTF[(0 * 16 + pp) * 4];
        const float* DX = &OUTF[(1 * 16 + pp) * 4];
        const float* DY = &OUTF[(2 * 16 + pp) * 4];
        const float* SXX = &OUTF[(3 * 16 + pp) * 4];
        const float* SYY = &OUTF[(4 * 16 + pp) * 4];
        float r = V[0],  P = V[1],  u = V[2],  v = V[3];
        float rx = DX[0], Px = DX[1], ux = DX[2], vx = DX[3];
        float ry = DY[0], Py = DY[1], uy = DY[2], vy = DY[3];
        float rxx = SXX[0], Pxx = SXX[1], uxx = SXX[2], vxx = SXX[3];
        float ryy = SYY[0], Pyy = SYY[1], uyy = SYY[2], vyy = SYY[3];
        const float GI = 2.5f;  // 1/(gamma-1)

        float q  = u * u + v * v;
        float E  = P * GI + 0.5f * r * q;
        float Ex = Px * GI + 0.5f * rx * q + r * (u * ux + v * vx);
        float Ey = Py * GI + 0.5f * ry * q + r * (u * uy + v * vy);
        float EpP = E + P;

        float f1x = rx * u + r * ux;
        float f2x = rx * u * u + 2.f * r * u * ux + Px;
        float f3x = rx * u * v + r * ux * v + r * u * vx;
        float f4x = ux * EpP + u * (Ex + Px);

        float g1y = ry * v + r * vy;
        float g2y = ry * u * v + r * uy * v + r * u * vy;
        float g3y = ry * v * v + 2.f * r * v * vy + Py;
        float g4y = vy * EpP + v * (Ey + Py);

        float qx  = 2.f * (u * ux + v * vx);
        float qy  = 2.f * (u * uy + v * vy);
        float qxx = 2.f * (ux * ux + u * uxx + vx * vx + v * vxx);
        float qyy = 2.f * (uy * uy + u * uyy + vy * vy + v * vyy);

        float U1s = rxx + ryy;
        float U2s = (rxx * u + 2.f * rx * ux + r * uxx)
                  + (ryy * u + 2.f * ry * uy + r * uyy);
        float U3s = (rxx * v + 2.f * rx * vx + r * vxx)
                  + (ryy * v + 2.f * ry * vy + r * vyy);
        float U4s = (Pxx + Pyy) * GI
                  + 0.5f * (rxx * q + 2.f * rx * qx + r * qxx
                          + ryy * q + 2.f * ry * qy + r * qyy);

        float mu = MUV[pp];
        float r1 = f1x + g1y - mu * U1s;
        float r2 = f2x + g2y - mu * U2s;
        float r3 = f3x + g3y - mu * U3s;
        float r4 = f4x + g4y - mu * U4s;

        contrib = (r1 * r1 + r2 * r2 + r3 * r3 + r4 * r4 + 0.1f * mu * mu)
                  * (1.0f / (float)NTRAIN);
    }
    if (t < 64) {
        contrib += __shfl_down(contrib, 32);
        contrib += __shfl_down(contrib, 16);
        contrib += __shfl_down(contrib, 8);
        contrib += __shfl_down(contrib, 4);
        contrib += __shfl_down(contrib, 2);
        contrib += __shfl_down(contrib, 1);
        if (t == 0) atomicAdd(out, contrib);
    }
}

// ---------------------------------------------------------------------------
// Boundary kernel: 256 threads/block, 64 points/block.
// blocks 0..63: inlet, 64..127: base, 128..191: top, 192..255: slipNormal.
// LDS state S[unit][point], row stride 69.
// Thread (pq = t>>4, c = t&15): 4 points (pq*4..+4) x 8 cols (c*8..+8).
// ---------------------------------------------------------------------------
__global__ __launch_bounds__(256) void boundary_kernel(
    const float* __restrict__ x_inlet, const float* __restrict__ U_inlet,
    const float* __restrict__ x_base,  const float* __restrict__ x_top,
    const float* __restrict__ x_slip,
    const float* __restrict__ W0, const float* __restrict__ b0,
    const float* __restrict__ W1, const float* __restrict__ b1,
    const float* __restrict__ W2, const float* __restrict__ b2,
    const float* __restrict__ W3, const float* __restrict__ b3,
    const float* __restrict__ W4, const float* __restrict__ b4,
    float* __restrict__ out)
{
    __shared__ float S[128 * 69];
    __shared__ float O4[64 * 4];

    const int t  = threadIdx.x;
    const int pq = t >> 4;  // 0..15, group of 4 points
    const int c  = t & 15;  // 0..15, 8 cols each

    const int batch = blockIdx.x >> 6;  // 0..3
    const int lb    = blockIdx.x & 63;
    const float* xs = (batch == 0) ? x_inlet
                    : (batch == 1) ? x_base
                    : (batch == 2) ? x_top : x_slip;
    const int base_pt = lb * 64;

    float xv[4], yv[4];
    #pragma unroll
    for (int i = 0; i < 4; i++) {
        float2 xy = *(const float2*)(xs + (base_pt + pq * 4 + i) * 2);
        xv[i] = xy.x; yv[i] = xy.y;
    }

    // layer 0: 2 -> 128
    #pragma unroll
    for (int j = 0; j < 8; j++) {
        int u = c * 8 + j;
        float w0 = W0[u], w1 = W0[128 + u], bb = b0[u];
        #pragma unroll
        for (int i = 0; i < 4; i++) {
            S[u * 69 + pq * 4 + i] = fast_tanh(xv[i] * w0 + yv[i] * w1 + bb);
        }
    }
    __syncthreads();

    // hidden layers 1..3
    const float* Ws[3] = { W1, W2, W3 };
    const float* Bs[3] = { b1, b2, b3 };
    for (int l = 0; l < 3; l++) {
        const float* __restrict__ W = Ws[l];
        float acc[4][8];
        #pragma unroll
        for (int i = 0; i < 4; i++)
            #pragma unroll
            for (int j = 0; j < 8; j++) acc[i][j] = Bs[l][c * 8 + j];
        const float* Sbase = &S[pq * 4];
        #pragma unroll 4
        for (int k = 0; k < 128; k++) {
            float a0 = Sbase[k * 69 + 0];
            float a1 = Sbase[k * 69 + 1];
            float a2 = Sbase[k * 69 + 2];
            float a3 = Sbase[k * 69 + 3];
            float4 wA = *(const float4*)(W + k * 128 + c * 8);
            float4 wB = *(const float4*)(W + k * 128 + c * 8 + 4);
            float w[8] = { wA.x, wA.y, wA.z, wA.w, wB.x, wB.y, wB.z, wB.w };
            #pragma unroll
            for (int j = 0; j < 8; j++) {
                acc[0][j] += a0 * w[j];
                acc[1][j] += a1 * w[j];
                acc[2][j] += a2 * w[j];
                acc[3][j] += a3 * w[j];
            }
        }
        __syncthreads();
        #pragma unroll
        for (int j = 0; j < 8; j++)
            #pragma unroll
            for (int i = 0; i < 4; i++)
                S[(c * 8 + j) * 69 + pq * 4 + i] = fast_tanh(acc[i][j]);
        __syncthreads();
    }

    // layer 4: 128 -> 4 ; thread t: point = t&63, output j = t>>6
    {
        int pp = t & 63, j = t >> 6;
        float a = b4[j];
        #pragma unroll 4
        for (int k = 0; k < 128; k++) a += S[k * 69 + pp] * W4[k * 4 + j];
        O4[pp * 4 + j] = a;
    }
    __syncthreads();

    float contrib = 0.f;
    if (t < 64) {
        int pp = t;
        float o0 = O4[pp * 4 + 0], o1 = O4[pp * 4 + 1];
        float o2 = O4[pp * 4 + 2], o3 = O4[pp * 4 + 3];
        float l;
        if (batch == 0) {
            float4 Ui = *(const float4*)(U_inlet + (base_pt + pp) * 4);
            float d0 = o0 - Ui.x, d1 = o1 - Ui.y, d2 = o2 - Ui.z, d3 = o3 - Ui.w;
            l = d0 * d0 + d1 * d1 + d2 * d2 + d3 * d3;
        } else if (batch == 3) {
            const float sa = -0.17364817766693033f;  // sin(-pi/18)
            const float ca =  0.9848077530122080f;   // cos(-pi/18)
            float d = -o2 * sa + o3 * ca;
            l = d * d;
        } else {
            l = o3 * o3;
        }
        contrib = 10.0f * l * (1.0f / (float)NBDY);
    }
    if (t < 64) {
        contrib += __shfl_down(contrib, 32);
        contrib += __shfl_down(contrib, 16);
        contrib += __shfl_down(contrib, 8);
        contrib += __shfl_down(contrib, 4);
        contrib += __shfl_down(contrib, 2);
        contrib += __shfl_down(contrib, 1);
        if (t == 0) atomicAdd(out, contrib);
    }
}

extern "C" void kernel_launch(void* const* d_in, const int* in_sizes, int n_in,
                              void* d_out, int out_size, void* d_ws, size_t ws_size,
                              hipStream_t stream) {
    const float* xt      = (const float*)d_in[0];
    const float* x_inlet = (const float*)d_in[1];
    const float* U_inlet = (const float*)d_in[2];
    const float* x_base  = (const float*)d_in[3];
    const float* x_top   = (const float*)d_in[4];
    const float* x_slip  = (const float*)d_in[5];
    const float* W0 = (const float*)d_in[6];
    const float* b0 = (const float*)d_in[7];
    const float* W1 = (const float*)d_in[8];
    const float* b1 = (const float*)d_in[9];
    const float* W2 = (const float*)d_in[10];
    const float* b2 = (const float*)d_in[11];
    const float* W3 = (const float*)d_in[12];
    const float* b3 = (const float*)d_in[13];
    const float* W4 = (const float*)d_in[14];
    const float* b4 = (const float*)d_in[15];
    const float* V0 = (const float*)d_in[16];
    const float* c0 = (const float*)d_in[17];
    const float* V1 = (const float*)d_in[18];
    const float* c1 = (const float*)d_in[19];
    const float* V2 = (const float*)d_in[20];
    const float* c2 = (const float*)d_in[21];
    float* out = (float*)d_out;

    hipMemsetAsync(out, 0, sizeof(float), stream);

    physics_kernel<<<NTRAIN / 16, 256, 0, stream>>>(
        xt, W0, b0, W1, b1, W2, b2, W3, b3, W4, b4,
        V0, c0, V1, c1, V2, c2, out);

    boundary_kernel<<<256, 256, 0, stream>>>(
        x_inlet, U_inlet, x_base, x_top, x_slip,
        W0, b0, W1, b1, W2, b2, W3, b3, W4, b4, out);
}

// Round 2
// 357.181 us; speedup vs baseline: 1.0331x; 1.0331x over previous
//
#include <hip/hip_runtime.h>

#define NTRAIN 32768
#define NBDY   4096
#define PHYS_BLOCKS (NTRAIN / 16)   // 2048
#define BDY_BLOCKS  256

__device__ __forceinline__ float fast_tanh(float z) {
    float e = __expf(2.0f * z);
    return 1.0f - 2.0f / (e + 1.0f);
}

union F4 { float4 v; float f[4]; };

// ---------------------------------------------------------------------------
// Fused kernel. Blocks [0, 2048): physics (16 pts/block, 5 AD streams).
// Blocks [2048, 2304): boundary batches (64 pts/block).
//
// Physics LDS layout: A[row][k], row = p*5 + s (80 rows), stride 132 floats.
//   s: 0=value 1=d/dx 2=d/dy 3=d2/dx2 4=d2/dy2
//   -> k-contiguous: ds_read_b128 in GEMM, ds_write_b128 in activation store.
// Thread (p = t>>4, c = t&15): tile = point p, 5 streams, cols c*8..c*8+7.
// ---------------------------------------------------------------------------
__global__ __launch_bounds__(256, 3) void fused_kernel(
    const float* __restrict__ xt,
    const float* __restrict__ x_inlet, const float* __restrict__ U_inlet,
    const float* __restrict__ x_base,  const float* __restrict__ x_top,
    const float* __restrict__ x_slip,
    const float* __restrict__ W0, const float* __restrict__ b0,
    const float* __restrict__ W1, const float* __restrict__ b1,
    const float* __restrict__ W2, const float* __restrict__ b2,
    const float* __restrict__ W3, const float* __restrict__ b3,
    const float* __restrict__ W4, const float* __restrict__ b4,
    const float* __restrict__ V0, const float* __restrict__ c0,
    const float* __restrict__ V1, const float* __restrict__ c1,
    const float* __restrict__ V2, const float* __restrict__ c2,
    float* __restrict__ out)
{
    __shared__ float SM[11536];   // 46144 B -> 3 blocks/CU (12 waves)
    const int t = threadIdx.x;

    if (blockIdx.x < PHYS_BLOCKS) {
        // =================== PHYSICS PATH ===================
        float* A    = SM;           // 80 rows x stride 132 = 10560 floats
        float* PART = SM + 10560;   // 160 x 4
        float* OUTF = SM + 11200;   // 80 x 4
        float* MUV  = SM + 11520;   // 16
        float* MU   = SM;           // mu MLP state, overlaps A (used first)

        const int p = t >> 4;   // point 0..15
        const int c = t & 15;   // col group 0..15

        const int ptIdx = blockIdx.x * 16 + p;
        const float2 xy = *(const float2*)(xt + ptIdx * 2);
        const float x = xy.x, y = xy.y;

        // ---------------- mu MLP (forward only), stride-17 layout ----------
        #pragma unroll
        for (int i = 0; i < 4; i++) {
            int u = c * 4 + i;
            float z = x * V0[u] + y * V0[64 + u] + c0[u];
            MU[u * 17 + p] = fast_tanh(z);
        }
        __syncthreads();
        {
            float acc[4];
            #pragma unroll
            for (int i = 0; i < 4; i++) acc[i] = c1[c * 4 + i];
            #pragma unroll 4
            for (int k = 0; k < 64; k++) {
                float a = MU[k * 17 + p];
                float4 w = *(const float4*)(V1 + k * 64 + c * 4);
                acc[0] += a * w.x; acc[1] += a * w.y;
                acc[2] += a * w.z; acc[3] += a * w.w;
            }
            __syncthreads();
            #pragma unroll
            for (int i = 0; i < 4; i++) MU[(c * 4 + i) * 17 + p] = fast_tanh(acc[i]);
        }
        __syncthreads();
        {
            float partial = 0.f;
            #pragma unroll
            for (int i = 0; i < 4; i++) {
                int k = c * 4 + i;
                partial += MU[k * 17 + p] * V2[k];
            }
            partial += __shfl_down(partial, 8);
            partial += __shfl_down(partial, 4);
            partial += __shfl_down(partial, 2);
            partial += __shfl_down(partial, 1);
            if (c == 0) {
                float s = partial + c2[0];
                MUV[p] = 0.01f * s * s;
            }
        }
        __syncthreads();

        const int rbase = p * 5 * 132;

        // ---------------- main MLP layer 0: 2 -> 128, 5 streams ------------
        {
            float n0[8], n1[8], n2[8], n3[8], n4[8];
            #pragma unroll
            for (int j = 0; j < 8; j++) {
                int u = c * 8 + j;
                float w0 = W0[u], w1 = W0[128 + u];
                float zv = x * w0 + y * w1 + b0[u];
                float tt = fast_tanh(zv);
                float s2 = 1.f - tt * tt;
                float m2 = -2.f * tt * s2;
                n0[j] = tt;
                n1[j] = s2 * w0;
                n2[j] = s2 * w1;
                n3[j] = m2 * w0 * w0;
                n4[j] = m2 * w1 * w1;
            }
            float* dst = &A[rbase + c * 8];
            *(float4*)(dst + 0*132)     = make_float4(n0[0], n0[1], n0[2], n0[3]);
            *(float4*)(dst + 0*132 + 4) = make_float4(n0[4], n0[5], n0[6], n0[7]);
            *(float4*)(dst + 1*132)     = make_float4(n1[0], n1[1], n1[2], n1[3]);
            *(float4*)(dst + 1*132 + 4) = make_float4(n1[4], n1[5], n1[6], n1[7]);
            *(float4*)(dst + 2*132)     = make_float4(n2[0], n2[1], n2[2], n2[3]);
            *(float4*)(dst + 2*132 + 4) = make_float4(n2[4], n2[5], n2[6], n2[7]);
            *(float4*)(dst + 3*132)     = make_float4(n3[0], n3[1], n3[2], n3[3]);
            *(float4*)(dst + 3*132 + 4) = make_float4(n3[4], n3[5], n3[6], n3[7]);
            *(float4*)(dst + 4*132)     = make_float4(n4[0], n4[1], n4[2], n4[3]);
            *(float4*)(dst + 4*132 + 4) = make_float4(n4[4], n4[5], n4[6], n4[7]);
        }
        __syncthreads();

        // ---------------- hidden layers 1..3: 128 -> 128, 5 streams --------
        const float* Ws[3] = { W1, W2, W3 };
        const float* Bs[3] = { b1, b2, b3 };
        #pragma unroll 1
        for (int l = 0; l < 3; l++) {
            const float* __restrict__ W = Ws[l];
            float acc0[8], acc1[8], acc2[8], acc3[8], acc4[8];
            #pragma unroll
            for (int j = 0; j < 8; j++) {
                acc0[j] = Bs[l][c * 8 + j];
                acc1[j] = 0.f; acc2[j] = 0.f; acc3[j] = 0.f; acc4[j] = 0.f;
            }
            #pragma unroll 2
            for (int k0 = 0; k0 < 128; k0 += 4) {
                F4 af[5];
                #pragma unroll
                for (int s = 0; s < 5; s++)
                    af[s].v = *(const float4*)&A[rbase + s * 132 + k0];
                const float* Wk = W + (k0 << 7) + (c << 3);
                F4 wk[8];
                #pragma unroll
                for (int kk = 0; kk < 4; kk++) {
                    wk[2*kk].v   = *(const float4*)(Wk + kk * 128);
                    wk[2*kk+1].v = *(const float4*)(Wk + kk * 128 + 4);
                }
                #pragma unroll
                for (int kk = 0; kk < 4; kk++) {
                    #pragma unroll
                    for (int j = 0; j < 8; j++) {
                        float w = wk[2*kk + (j >> 2)].f[j & 3];
                        acc0[j] += af[0].f[kk] * w;
                        acc1[j] += af[1].f[kk] * w;
                        acc2[j] += af[2].f[kk] * w;
                        acc3[j] += af[3].f[kk] * w;
                        acc4[j] += af[4].f[kk] * w;
                    }
                }
            }
            // transform (registers only)
            #pragma unroll
            for (int j = 0; j < 8; j++) {
                float tt = fast_tanh(acc0[j]);
                float s2 = 1.f - tt * tt;
                float m2 = -2.f * tt * s2;
                float gx = acc1[j], gy = acc2[j];
                acc0[j] = tt;
                acc1[j] = s2 * gx;
                acc2[j] = s2 * gy;
                acc3[j] = s2 * acc3[j] + m2 * gx * gx;
                acc4[j] = s2 * acc4[j] + m2 * gy * gy;
            }
            __syncthreads();   // all reads of A done before overwriting
            float* dst = &A[rbase + c * 8];
            *(float4*)(dst + 0*132)     = make_float4(acc0[0], acc0[1], acc0[2], acc0[3]);
            *(float4*)(dst + 0*132 + 4) = make_float4(acc0[4], acc0[5], acc0[6], acc0[7]);
            *(float4*)(dst + 1*132)     = make_float4(acc1[0], acc1[1], acc1[2], acc1[3]);
            *(float4*)(dst + 1*132 + 4) = make_float4(acc1[4], acc1[5], acc1[6], acc1[7]);
            *(float4*)(dst + 2*132)     = make_float4(acc2[0], acc2[1], acc2[2], acc2[3]);
            *(float4*)(dst + 2*132 + 4) = make_float4(acc2[4], acc2[5], acc2[6], acc2[7]);
            *(float4*)(dst + 3*132)     = make_float4(acc3[0], acc3[1], acc3[2], acc3[3]);
            *(float4*)(dst + 3*132 + 4) = make_float4(acc3[4], acc3[5], acc3[6], acc3[7]);
            *(float4*)(dst + 4*132)     = make_float4(acc4[0], acc4[1], acc4[2], acc4[3]);
            *(float4*)(dst + 4*132 + 4) = make_float4(acc4[4], acc4[5], acc4[6], acc4[7]);
            __syncthreads();
        }

        // ---------------- layer 4: 128 -> 4 (linear), k-split 2 ------------
        if (t < 160) {
            int r    = t >> 1;   // row 0..79 = p*5+s
            int half = t & 1;
            float a0 = 0.f, a1 = 0.f, a2 = 0.f, a3 = 0.f;
            if (half == 0 && (r % 5) == 0) { a0 = b4[0]; a1 = b4[1]; a2 = b4[2]; a3 = b4[3]; }
            const float* Ar = &A[r * 132 + half * 64];
            const float* W4h = W4 + half * 256;
            #pragma unroll 4
            for (int k0 = 0; k0 < 64; k0 += 4) {
                F4 av; av.v = *(const float4*)(Ar + k0);
                #pragma unroll
                for (int kk = 0; kk < 4; kk++) {
                    float4 w = *(const float4*)(W4h + (k0 + kk) * 4);
                    a0 += av.f[kk] * w.x; a1 += av.f[kk] * w.y;
                    a2 += av.f[kk] * w.z; a3 += av.f[kk] * w.w;
                }
            }
            *(float4*)&PART[t * 4] = make_float4(a0, a1, a2, a3);
        }
        __syncthreads();
        if (t < 80) {
            float4 u0 = *(float4*)&PART[(2 * t) * 4];
            float4 u1 = *(float4*)&PART[(2 * t + 1) * 4];
            *(float4*)&OUTF[t * 4] =
                make_float4(u0.x + u1.x, u0.y + u1.y, u0.z + u1.z, u0.w + u1.w);
        }
        __syncthreads();

        // ---------------- per-point residual + reduction -------------------
        float contrib = 0.f;
        if (t < 16) {
            const int pp = t;
            const float* V   = &OUTF[(pp * 5 + 0) * 4];
            const float* DX  = &OUTF[(pp * 5 + 1) * 4];
            const float* DY  = &OUTF[(pp * 5 + 2) * 4];
            const float* SXX = &OUTF[(pp * 5 + 3) * 4];
            const float* SYY = &OUTF[(pp * 5 + 4) * 4];
            float r = V[0],  P = V[1],  u = V[2],  v = V[3];
            float rx = DX[0], Px = DX[1], ux = DX[2], vx = DX[3];
            float ry = DY[0], Py = DY[1], uy = DY[2], vy = DY[3];
            float rxx = SXX[0], Pxx = SXX[1], uxx = SXX[2], vxx = SXX[3];
            float ryy = SYY[0], Pyy = SYY[1], uyy = SYY[2], vyy = SYY[3];
            const float GI = 2.5f;  // 1/(gamma-1)

            float q  = u * u + v * v;
            float E  = P * GI + 0.5f * r * q;
            float Ex = Px * GI + 0.5f * rx * q + r * (u * ux + v * vx);
            float Ey = Py * GI + 0.5f * ry * q + r * (u * uy + v * vy);
            float EpP = E + P;

            float f1x = rx * u + r * ux;
            float f2x = rx * u * u + 2.f * r * u * ux + Px;
            float f3x = rx * u * v + r * ux * v + r * u * vx;
            float f4x = ux * EpP + u * (Ex + Px);

            float g1y = ry * v + r * vy;
            float g2y = ry * u * v + r * uy * v + r * u * vy;
            float g3y = ry * v * v + 2.f * r * v * vy + Py;
            float g4y = vy * EpP + v * (Ey + Py);

            float qx  = 2.f * (u * ux + v * vx);
            float qy  = 2.f * (u * uy + v * vy);
            float qxx = 2.f * (ux * ux + u * uxx + vx * vx + v * vxx);
            float qyy = 2.f * (uy * uy + u * uyy + vy * vy + v * vyy);

            float U1s = rxx + ryy;
            float U2s = (rxx * u + 2.f * rx * ux + r * uxx)
                      + (ryy * u + 2.f * ry * uy + r * uyy);
            float U3s = (rxx * v + 2.f * rx * vx + r * vxx)
                      + (ryy * v + 2.f * ry * vy + r * vyy);
            float U4s = (Pxx + Pyy) * GI
                      + 0.5f * (rxx * q + 2.f * rx * qx + r * qxx
                              + ryy * q + 2.f * ry * qy + r * qyy);

            float mu = MUV[pp];
            float r1 = f1x + g1y - mu * U1s;
            float r2 = f2x + g2y - mu * U2s;
            float r3 = f3x + g3y - mu * U3s;
            float r4 = f4x + g4y - mu * U4s;

            contrib = (r1 * r1 + r2 * r2 + r3 * r3 + r4 * r4 + 0.1f * mu * mu)
                      * (1.0f / (float)NTRAIN);
        }
        if (t < 64) {
            contrib += __shfl_down(contrib, 32);
            contrib += __shfl_down(contrib, 16);
            contrib += __shfl_down(contrib, 8);
            contrib += __shfl_down(contrib, 4);
            contrib += __shfl_down(contrib, 2);
            contrib += __shfl_down(contrib, 1);
            if (t == 0) atomicAdd(out, contrib);
        }
    } else {
        // =================== BOUNDARY PATH ===================
        float* S  = SM;           // 128 x stride 69 = 8832 floats
        float* O4 = SM + 8832;    // 64 x 4

        const int pq = t >> 4;  // 0..15, group of 4 points
        const int c  = t & 15;  // 0..15, 8 cols each

        const int bb    = blockIdx.x - PHYS_BLOCKS;
        const int batch = bb >> 6;  // 0..3
        const int lb    = bb & 63;
        const float* xs = (batch == 0) ? x_inlet
                        : (batch == 1) ? x_base
                        : (batch == 2) ? x_top : x_slip;
        const int base_pt = lb * 64;

        float xv[4], yv[4];
        #pragma unroll
        for (int i = 0; i < 4; i++) {
            float2 xy = *(const float2*)(xs + (base_pt + pq * 4 + i) * 2);
            xv[i] = xy.x; yv[i] = xy.y;
        }

        // layer 0: 2 -> 128
        #pragma unroll
        for (int j = 0; j < 8; j++) {
            int u = c * 8 + j;
            float w0 = W0[u], w1 = W0[128 + u], bb2 = b0[u];
            #pragma unroll
            for (int i = 0; i < 4; i++) {
                S[u * 69 + pq * 4 + i] = fast_tanh(xv[i] * w0 + yv[i] * w1 + bb2);
            }
        }
        __syncthreads();

        const float* Ws[3] = { W1, W2, W3 };
        const float* Bs[3] = { b1, b2, b3 };
        #pragma unroll 1
        for (int l = 0; l < 3; l++) {
            const float* __restrict__ W = Ws[l];
            float acc[4][8];
            #pragma unroll
            for (int i = 0; i < 4; i++)
                #pragma unroll
                for (int j = 0; j < 8; j++) acc[i][j] = Bs[l][c * 8 + j];
            const float* Sbase = &S[pq * 4];
            #pragma unroll 4
            for (int k = 0; k < 128; k++) {
                float a0 = Sbase[k * 69 + 0];
                float a1 = Sbase[k * 69 + 1];
                float a2 = Sbase[k * 69 + 2];
                float a3 = Sbase[k * 69 + 3];
                float4 wA = *(const float4*)(W + k * 128 + c * 8);
                float4 wB = *(const float4*)(W + k * 128 + c * 8 + 4);
                float w[8] = { wA.x, wA.y, wA.z, wA.w, wB.x, wB.y, wB.z, wB.w };
                #pragma unroll
                for (int j = 0; j < 8; j++) {
                    acc[0][j] += a0 * w[j];
                    acc[1][j] += a1 * w[j];
                    acc[2][j] += a2 * w[j];
                    acc[3][j] += a3 * w[j];
                }
            }
            __syncthreads();
            #pragma unroll
            for (int j = 0; j < 8; j++)
                #pragma unroll
                for (int i = 0; i < 4; i++)
                    S[(c * 8 + j) * 69 + pq * 4 + i] = fast_tanh(acc[i][j]);
            __syncthreads();
        }

        // layer 4: 128 -> 4 ; thread t: point = t&63, output j = t>>6
        {
            int pp = t & 63, j = t >> 6;
            float a = b4[j];
            #pragma unroll 4
            for (int k = 0; k < 128; k++) a += S[k * 69 + pp] * W4[k * 4 + j];
            O4[pp * 4 + j] = a;
        }
        __syncthreads();

        float contrib = 0.f;
        if (t < 64) {
            int pp = t;
            float o0 = O4[pp * 4 + 0], o1 = O4[pp * 4 + 1];
            float o2 = O4[pp * 4 + 2], o3 = O4[pp * 4 + 3];
            float l;
            if (batch == 0) {
                float4 Ui = *(const float4*)(U_inlet + (base_pt + pp) * 4);
                float d0 = o0 - Ui.x, d1 = o1 - Ui.y, d2 = o2 - Ui.z, d3 = o3 - Ui.w;
                l = d0 * d0 + d1 * d1 + d2 * d2 + d3 * d3;
            } else if (batch == 3) {
                const float sa = -0.17364817766693033f;  // sin(-pi/18)
                const float ca =  0.9848077530122080f;   // cos(-pi/18)
                float d = -o2 * sa + o3 * ca;
                l = d * d;
            } else {
                l = o3 * o3;
            }
            contrib = 10.0f * l * (1.0f / (float)NBDY);
        }
        if (t < 64) {
            contrib += __shfl_down(contrib, 32);
            contrib += __shfl_down(contrib, 16);
            contrib += __shfl_down(contrib, 8);
            contrib += __shfl_down(contrib, 4);
            contrib += __shfl_down(contrib, 2);
            contrib += __shfl_down(contrib, 1);
            if (t == 0) atomicAdd(out, contrib);
        }
    }
}

extern "C" void kernel_launch(void* const* d_in, const int* in_sizes, int n_in,
                              void* d_out, int out_size, void* d_ws, size_t ws_size,
                              hipStream_t stream) {
    const float* xt      = (const float*)d_in[0];
    const float* x_inlet = (const float*)d_in[1];
    const float* U_inlet = (const float*)d_in[2];
    const float* x_base  = (const float*)d_in[3];
    const float* x_top   = (const float*)d_in[4];
    const float* x_slip  = (const float*)d_in[5];
    const float* W0 = (const float*)d_in[6];
    const float* b0 = (const float*)d_in[7];
    const float* W1 = (const float*)d_in[8];
    const float* b1 = (const float*)d_in[9];
    const float* W2 = (const float*)d_in[10];
    const float* b2 = (const float*)d_in[11];
    const float* W3 = (const float*)d_in[12];
    const float* b3 = (const float*)d_in[13];
    const float* W4 = (const float*)d_in[14];
    const float* b4 = (const float*)d_in[15];
    const float* V0 = (const float*)d_in[16];
    const float* c0 = (const float*)d_in[17];
    const float* V1 = (const float*)d_in[18];
    const float* c1 = (const float*)d_in[19];
    const float* V2 = (const float*)d_in[20];
    const float* c2 = (const float*)d_in[21];
    float* out = (float*)d_out;

    hipMemsetAsync(out, 0, sizeof(float), stream);

    fused_kernel<<<PHYS_BLOCKS + BDY_BLOCKS, 256, 0, stream>>>(
        xt, x_inlet, U_inlet, x_base, x_top, x_slip,
        W0, b0, W1, b1, W2, b2, W3, b3, W4, b4,
        V0, c0, V1, c1, V2, c2, out);
}

// Round 3
// 226.450 us; speedup vs baseline: 1.6295x; 1.5773x over previous
//
#include <hip/hip_runtime.h>

#define NTRAIN 32768
#define NBDY   4096
#define PHYS_BLOCKS (NTRAIN / 16)   // 2048
#define BDY_BLOCKS  256

typedef __bf16 bf16x8 __attribute__((ext_vector_type(8)));
typedef float  f32x4  __attribute__((ext_vector_type(4)));

union FragU { uint4 q; bf16x8 b; __bf16 e[8]; };
union F4 { float4 v; float f[4]; };

__device__ __forceinline__ float fast_tanh(float z) {
    float e = __expf(2.0f * z);
    return 1.0f - 2.0f / (e + 1.0f);
}

// ---------------------------------------------------------------------------
// Pack W1..W3 into MFMA B-fragment order, split into bf16 hi/lo.
// Per layer: idx = ((nt*4 + ks)*64 + lane)*8 + j
//   value = W[ks*32 + (lane>>4)*8 + j][nt*16 + (lane&15)]
// hi at wsU + l*32768, lo at +16384 (ushort units). Total 192 KB.
// ---------------------------------------------------------------------------
__global__ __launch_bounds__(256) void pack_w_kernel(
    const float* __restrict__ W1, const float* __restrict__ W2,
    const float* __restrict__ W3, unsigned short* __restrict__ wsU)
{
    int l   = blockIdx.x >> 3;   // 0..2
    int sub = blockIdx.x & 7;    // 0..7
    const float* W = (l == 0) ? W1 : (l == 1) ? W2 : W3;
    __bf16* hi = (__bf16*)(wsU + l * 32768);
    __bf16* lo = hi + 16384;
    int idx = sub * 2048 + threadIdx.x;
    #pragma unroll
    for (int it = 0; it < 8; it++, idx += 256) {
        int j    = idx & 7;
        int lane = (idx >> 3) & 63;
        int ks   = (idx >> 9) & 3;
        int nt   = idx >> 11;
        int k = ks * 32 + (lane >> 4) * 8 + j;
        int n = nt * 16 + (lane & 15);
        float v = W[k * 128 + n];
        __bf16 h = (__bf16)v;
        hi[idx] = h;
        lo[idx] = (__bf16)(v - (float)h);
    }
}

// ---------------------------------------------------------------------------
// Fused kernel. Blocks [0, 2048): physics. Blocks [2048, 2304): boundary.
//
// Physics: 16 pts/block, rows stream-major r = s*16 + p (s: 0=val 1=dx 2=dy
// 3=dxx 4=dyy). A stored bf16 hi/lo in LDS, row stride 136 bf16.
// Hidden layers via mfma_f32_16x16x32_bf16, 3-pass split (Ah*Wh+Al*Wh+Ah*Wl).
// Wave wv owns ntiles {2wv, 2wv+1} x all 5 stream-tiles -> transform is
// lane-local (lane holds all 5 streams of its 4 (point,unit) pairs).
// ---------------------------------------------------------------------------
__global__ __launch_bounds__(256, 3) void fused_kernel(
    const float* __restrict__ xt,
    const float* __restrict__ x_inlet, const float* __restrict__ U_inlet,
    const float* __restrict__ x_base,  const float* __restrict__ x_top,
    const float* __restrict__ x_slip,
    const float* __restrict__ W0, const float* __restrict__ b0,
    const float* __restrict__ W1, const float* __restrict__ b1,
    const float* __restrict__ W2, const float* __restrict__ b2,
    const float* __restrict__ W3, const float* __restrict__ b3,
    const float* __restrict__ W4, const float* __restrict__ b4,
    const float* __restrict__ V0, const float* __restrict__ c0,
    const float* __restrict__ V1, const float* __restrict__ c1,
    const float* __restrict__ V2, const float* __restrict__ c2,
    const unsigned short* __restrict__ wsU,
    float* __restrict__ out)
{
    __shared__ float SM[11856];   // 47424 B -> 3 blocks/CU
    const int t = threadIdx.x;

    if (blockIdx.x < PHYS_BLOCKS) {
        // =================== PHYSICS PATH ===================
        // A region: floats [0,10880) = Ah (10880 bf16) + Al (10880 bf16)
        unsigned short* AhU = (unsigned short*)SM;
        unsigned short* AlU = AhU + 10880;
        __bf16* AhB = (__bf16*)SM;
        __bf16* AlB = AhB + 10880;
        float* PART = SM + 10880;   // 160 x 4
        float* OUTF = SM + 11520;   // 80 x 4
        float* MUV  = SM + 11840;   // 16
        float* MU   = SM;           // mu MLP state, overlaps A (used first)

        const int p = t >> 4;   // point 0..15
        const int c = t & 15;   // col group 0..15

        const int ptIdx = blockIdx.x * 16 + p;
        const float2 xy = *(const float2*)(xt + ptIdx * 2);
        const float x = xy.x, y = xy.y;

        // ---------------- mu MLP (forward only), stride-17 layout ----------
        #pragma unroll
        for (int i = 0; i < 4; i++) {
            int u = c * 4 + i;
            float z = x * V0[u] + y * V0[64 + u] + c0[u];
            MU[u * 17 + p] = fast_tanh(z);
        }
        __syncthreads();
        {
            float acc[4];
            #pragma unroll
            for (int i = 0; i < 4; i++) acc[i] = c1[c * 4 + i];
            #pragma unroll 4
            for (int k = 0; k < 64; k++) {
                float a = MU[k * 17 + p];
                float4 w = *(const float4*)(V1 + k * 64 + c * 4);
                acc[0] += a * w.x; acc[1] += a * w.y;
                acc[2] += a * w.z; acc[3] += a * w.w;
            }
            __syncthreads();
            #pragma unroll
            for (int i = 0; i < 4; i++) MU[(c * 4 + i) * 17 + p] = fast_tanh(acc[i]);
        }
        __syncthreads();
        {
            float partial = 0.f;
            #pragma unroll
            for (int i = 0; i < 4; i++) {
                int k = c * 4 + i;
                partial += MU[k * 17 + p] * V2[k];
            }
            partial += __shfl_down(partial, 8);
            partial += __shfl_down(partial, 4);
            partial += __shfl_down(partial, 2);
            partial += __shfl_down(partial, 1);
            if (c == 0) {
                float s = partial + c2[0];
                MUV[p] = 0.01f * s * s;
            }
        }
        __syncthreads();

        // ---------------- layer 0: 2 -> 128, 5 streams, write bf16 hi/lo ---
        {
            float vals[5][8];
            #pragma unroll
            for (int j = 0; j < 8; j++) {
                int u = c * 8 + j;
                float w0 = W0[u], w1 = W0[128 + u];
                float zv = x * w0 + y * w1 + b0[u];
                float tt = fast_tanh(zv);
                float s2 = 1.f - tt * tt;
                float m2 = -2.f * tt * s2;
                vals[0][j] = tt;
                vals[1][j] = s2 * w0;
                vals[2][j] = s2 * w1;
                vals[3][j] = m2 * w0 * w0;
                vals[4][j] = m2 * w1 * w1;
            }
            #pragma unroll
            for (int s = 0; s < 5; s++) {
                FragU fh, fl;
                #pragma unroll
                for (int j = 0; j < 8; j++) {
                    __bf16 h = (__bf16)vals[s][j];
                    fh.e[j] = h;
                    fl.e[j] = (__bf16)(vals[s][j] - (float)h);
                }
                int off = (s * 16 + p) * 136 + c * 8;
                *(uint4*)(AhU + off) = fh.q;
                *(uint4*)(AlU + off) = fl.q;
            }
        }
        __syncthreads();

        // ---------------- hidden layers 1..3 via MFMA ----------------------
        const int wv   = t >> 6;     // wave 0..3 -> ntiles {2wv, 2wv+1}
        const int lane = t & 63;
        const int mm   = lane & 15;  // C col / A row-in-tile
        const int q    = lane >> 4;  // quad
        const float* Bsl[3] = { b1, b2, b3 };

        #pragma unroll 1
        for (int l = 0; l < 3; l++) {
            const unsigned short* WpL = wsU + l * 32768;  // hi; lo at +16384
            f32x4 acc[2][5];
            #pragma unroll
            for (int i = 0; i < 2; i++)
                #pragma unroll
                for (int s = 0; s < 5; s++) {
                    acc[i][s][0] = 0.f; acc[i][s][1] = 0.f;
                    acc[i][s][2] = 0.f; acc[i][s][3] = 0.f;
                }
            #pragma unroll
            for (int ks = 0; ks < 4; ks++) {
                FragU ah[5], al[5];
                #pragma unroll
                for (int s = 0; s < 5; s++) {
                    int off = (s * 16 + mm) * 136 + ks * 32 + q * 8;
                    ah[s].q = *(const uint4*)(AhU + off);
                    al[s].q = *(const uint4*)(AlU + off);
                }
                FragU wh[2], wl[2];
                #pragma unroll
                for (int i = 0; i < 2; i++) {
                    int nt = 2 * wv + i;
                    const unsigned short* base =
                        WpL + (((nt * 4 + ks) * 64 + lane) << 3);
                    wh[i].q = *(const uint4*)base;
                    wl[i].q = *(const uint4*)(base + 16384);
                }
                #pragma unroll
                for (int i = 0; i < 2; i++)
                    #pragma unroll
                    for (int s = 0; s < 5; s++) {
                        acc[i][s] = __builtin_amdgcn_mfma_f32_16x16x32_bf16(
                            ah[s].b, wh[i].b, acc[i][s], 0, 0, 0);
                        acc[i][s] = __builtin_amdgcn_mfma_f32_16x16x32_bf16(
                            al[s].b, wh[i].b, acc[i][s], 0, 0, 0);
                        acc[i][s] = __builtin_amdgcn_mfma_f32_16x16x32_bf16(
                            ah[s].b, wl[i].b, acc[i][s], 0, 0, 0);
                    }
            }
            __syncthreads();   // all A reads done before overwrite
            // lane-local transform: C layout col=lane&15, row=q*4+reg
            #pragma unroll
            for (int i = 0; i < 2; i++) {
                int u = (2 * wv + i) * 16 + mm;
                float bias = Bsl[l][u];
                #pragma unroll
                for (int r = 0; r < 4; r++) {
                    int pp = q * 4 + r;
                    float z   = acc[i][0][r] + bias;
                    float zx  = acc[i][1][r], zy  = acc[i][2][r];
                    float zxx = acc[i][3][r], zyy = acc[i][4][r];
                    float tt = fast_tanh(z);
                    float s2 = 1.f - tt * tt;
                    float m2 = -2.f * tt * s2;
                    float vals[5];
                    vals[0] = tt;
                    vals[1] = s2 * zx;
                    vals[2] = s2 * zy;
                    vals[3] = s2 * zxx + m2 * zx * zx;
                    vals[4] = s2 * zyy + m2 * zy * zy;
                    #pragma unroll
                    for (int s = 0; s < 5; s++) {
                        int off = (s * 16 + pp) * 136 + u;
                        __bf16 h = (__bf16)vals[s];
                        AhB[off] = h;
                        AlB[off] = (__bf16)(vals[s] - (float)h);
                    }
                }
            }
            __syncthreads();
        }

        // ---------------- layer 4: 128 -> 4 (linear), k-split 2 ------------
        if (t < 160) {
            int r    = t >> 1;   // row 0..79 = s*16 + p
            int half = t & 1;
            float a0 = 0.f, a1 = 0.f, a2 = 0.f, a3 = 0.f;
            if (half == 0 && r < 16) { a0 = b4[0]; a1 = b4[1]; a2 = b4[2]; a3 = b4[3]; }
            const int abase = r * 136 + half * 64;
            const float* W4h = W4 + half * 256;
            #pragma unroll
            for (int k0 = 0; k0 < 64; k0 += 8) {
                FragU qh, ql;
                qh.q = *(const uint4*)(AhU + abase + k0);
                ql.q = *(const uint4*)(AlU + abase + k0);
                #pragma unroll
                for (int j = 0; j < 8; j++) {
                    float a = (float)qh.e[j] + (float)ql.e[j];
                    float4 w = *(const float4*)(W4h + (k0 + j) * 4);
                    a0 += a * w.x; a1 += a * w.y; a2 += a * w.z; a3 += a * w.w;
                }
            }
            *(float4*)&PART[t * 4] = make_float4(a0, a1, a2, a3);
        }
        __syncthreads();
        if (t < 80) {
            float4 u0 = *(float4*)&PART[(2 * t) * 4];
            float4 u1 = *(float4*)&PART[(2 * t + 1) * 4];
            *(float4*)&OUTF[t * 4] =
                make_float4(u0.x + u1.x, u0.y + u1.y, u0.z + u1.z, u0.w + u1.w);
        }
        __syncthreads();

        // ---------------- per-point residual + reduction -------------------
        float contrib = 0.f;
        if (t < 16) {
            const int pp = t;
            const float* V   = &OUTF[(0  + pp) * 4];
            const float* DX  = &OUTF[(16 + pp) * 4];
            const float* DY  = &OUTF[(32 + pp) * 4];
            const float* SXX = &OUTF[(48 + pp) * 4];
            const float* SYY = &OUTF[(64 + pp) * 4];
            float r = V[0],  P = V[1],  u = V[2],  v = V[3];
            float rx = DX[0], Px = DX[1], ux = DX[2], vx = DX[3];
            float ry = DY[0], Py = DY[1], uy = DY[2], vy = DY[3];
            float rxx = SXX[0], Pxx = SXX[1], uxx = SXX[2], vxx = SXX[3];
            float ryy = SYY[0], Pyy = SYY[1], uyy = SYY[2], vyy = SYY[3];
            const float GI = 2.5f;  // 1/(gamma-1)

            float q2  = u * u + v * v;
            float E  = P * GI + 0.5f * r * q2;
            float Ex = Px * GI + 0.5f * rx * q2 + r * (u * ux + v * vx);
            float Ey = Py * GI + 0.5f * ry * q2 + r * (u * uy + v * vy);
            float EpP = E + P;

            float f1x = rx * u + r * ux;
            float f2x = rx * u * u + 2.f * r * u * ux + Px;
            float f3x = rx * u * v + r * ux * v + r * u * vx;
            float f4x = ux * EpP + u * (Ex + Px);

            float g1y = ry * v + r * vy;
            float g2y = ry * u * v + r * uy * v + r * u * vy;
            float g3y = ry * v * v + 2.f * r * v * vy + Py;
            float g4y = vy * EpP + v * (Ey + Py);

            float qx  = 2.f * (u * ux + v * vx);
            float qy  = 2.f * (u * uy + v * vy);
            float qxx = 2.f * (ux * ux + u * uxx + vx * vx + v * vxx);
            float qyy = 2.f * (uy * uy + u * uyy + vy * vy + v * vyy);

            float U1s = rxx + ryy;
            float U2s = (rxx * u + 2.f * rx * ux + r * uxx)
                      + (ryy * u + 2.f * ry * uy + r * uyy);
            float U3s = (rxx * v + 2.f * rx * vx + r * vxx)
                      + (ryy * v + 2.f * ry * vy + r * vyy);
            float U4s = (Pxx + Pyy) * GI
                      + 0.5f * (rxx * q2 + 2.f * rx * qx + r * qxx
                              + ryy * q2 + 2.f * ry * qy + r * qyy);

            float mu = MUV[pp];
            float r1 = f1x + g1y - mu * U1s;
            float r2 = f2x + g2y - mu * U2s;
            float r3 = f3x + g3y - mu * U3s;
            float r4 = f4x + g4y - mu * U4s;

            contrib = (r1 * r1 + r2 * r2 + r3 * r3 + r4 * r4 + 0.1f * mu * mu)
                      * (1.0f / (float)NTRAIN);
        }
        if (t < 64) {
            contrib += __shfl_down(contrib, 32);
            contrib += __shfl_down(contrib, 16);
            contrib += __shfl_down(contrib, 8);
            contrib += __shfl_down(contrib, 4);
            contrib += __shfl_down(contrib, 2);
            contrib += __shfl_down(contrib, 1);
            if (t == 0) atomicAdd(out, contrib);
        }
    } else {
        // =================== BOUNDARY PATH (fp32, unchanged) ===============
        float* S  = SM;           // 128 x stride 69 = 8832 floats
        float* O4 = SM + 8832;    // 64 x 4

        const int pq = t >> 4;
        const int c  = t & 15;

        const int bb    = blockIdx.x - PHYS_BLOCKS;
        const int batch = bb >> 6;
        const int lb    = bb & 63;
        const float* xs = (batch == 0) ? x_inlet
                        : (batch == 1) ? x_base
                        : (batch == 2) ? x_top : x_slip;
        const int base_pt = lb * 64;

        float xv[4], yv[4];
        #pragma unroll
        for (int i = 0; i < 4; i++) {
            float2 xy = *(const float2*)(xs + (base_pt + pq * 4 + i) * 2);
            xv[i] = xy.x; yv[i] = xy.y;
        }

        #pragma unroll
        for (int j = 0; j < 8; j++) {
            int u = c * 8 + j;
            float w0 = W0[u], w1 = W0[128 + u], bb2 = b0[u];
            #pragma unroll
            for (int i = 0; i < 4; i++) {
                S[u * 69 + pq * 4 + i] = fast_tanh(xv[i] * w0 + yv[i] * w1 + bb2);
            }
        }
        __syncthreads();

        const float* Ws[3] = { W1, W2, W3 };
        const float* Bs[3] = { b1, b2, b3 };
        #pragma unroll 1
        for (int l = 0; l < 3; l++) {
            const float* __restrict__ W = Ws[l];
            float acc[4][8];
            #pragma unroll
            for (int i = 0; i < 4; i++)
                #pragma unroll
                for (int j = 0; j < 8; j++) acc[i][j] = Bs[l][c * 8 + j];
            const float* Sbase = &S[pq * 4];
            #pragma unroll 4
            for (int k = 0; k < 128; k++) {
                float a0 = Sbase[k * 69 + 0];
                float a1 = Sbase[k * 69 + 1];
                float a2 = Sbase[k * 69 + 2];
                float a3 = Sbase[k * 69 + 3];
                float4 wA = *(const float4*)(W + k * 128 + c * 8);
                float4 wB = *(const float4*)(W + k * 128 + c * 8 + 4);
                float w[8] = { wA.x, wA.y, wA.z, wA.w, wB.x, wB.y, wB.z, wB.w };
                #pragma unroll
                for (int j = 0; j < 8; j++) {
                    acc[0][j] += a0 * w[j];
                    acc[1][j] += a1 * w[j];
                    acc[2][j] += a2 * w[j];
                    acc[3][j] += a3 * w[j];
                }
            }
            __syncthreads();
            #pragma unroll
            for (int j = 0; j < 8; j++)
                #pragma unroll
                for (int i = 0; i < 4; i++)
                    S[(c * 8 + j) * 69 + pq * 4 + i] = fast_tanh(acc[i][j]);
            __syncthreads();
        }

        {
            int pp = t & 63, j = t >> 6;
            float a = b4[j];
            #pragma unroll 4
            for (int k = 0; k < 128; k++) a += S[k * 69 + pp] * W4[k * 4 + j];
            O4[pp * 4 + j] = a;
        }
        __syncthreads();

        float contrib = 0.f;
        if (t < 64) {
            int pp = t;
            float o0 = O4[pp * 4 + 0], o1 = O4[pp * 4 + 1];
            float o2 = O4[pp * 4 + 2], o3 = O4[pp * 4 + 3];
            float l;
            if (batch == 0) {
                float4 Ui = *(const float4*)(U_inlet + (base_pt + pp) * 4);
                float d0 = o0 - Ui.x, d1 = o1 - Ui.y, d2 = o2 - Ui.z, d3 = o3 - Ui.w;
                l = d0 * d0 + d1 * d1 + d2 * d2 + d3 * d3;
            } else if (batch == 3) {
                const float sa = -0.17364817766693033f;
                const float ca =  0.9848077530122080f;
                float d = -o2 * sa + o3 * ca;
                l = d * d;
            } else {
                l = o3 * o3;
            }
            contrib = 10.0f * l * (1.0f / (float)NBDY);
        }
        if (t < 64) {
            contrib += __shfl_down(contrib, 32);
            contrib += __shfl_down(contrib, 16);
            contrib += __shfl_down(contrib, 8);
            contrib += __shfl_down(contrib, 4);
            contrib += __shfl_down(contrib, 2);
            contrib += __shfl_down(contrib, 1);
            if (t == 0) atomicAdd(out, contrib);
        }
    }
}

extern "C" void kernel_launch(void* const* d_in, const int* in_sizes, int n_in,
                              void* d_out, int out_size, void* d_ws, size_t ws_size,
                              hipStream_t stream) {
    const float* xt      = (const float*)d_in[0];
    const float* x_inlet = (const float*)d_in[1];
    const float* U_inlet = (const float*)d_in[2];
    const float* x_base  = (const float*)d_in[3];
    const float* x_top   = (const float*)d_in[4];
    const float* x_slip  = (const float*)d_in[5];
    const float* W0 = (const float*)d_in[6];
    const float* b0 = (const float*)d_in[7];
    const float* W1 = (const float*)d_in[8];
    const float* b1 = (const float*)d_in[9];
    const float* W2 = (const float*)d_in[10];
    const float* b2 = (const float*)d_in[11];
    const float* W3 = (const float*)d_in[12];
    const float* b3 = (const float*)d_in[13];
    const float* W4 = (const float*)d_in[14];
    const float* b4 = (const float*)d_in[15];
    const float* V0 = (const float*)d_in[16];
    const float* c0 = (const float*)d_in[17];
    const float* V1 = (const float*)d_in[18];
    const float* c1 = (const float*)d_in[19];
    const float* V2 = (const float*)d_in[20];
    const float* c2 = (const float*)d_in[21];
    float* out = (float*)d_out;
    unsigned short* wsU = (unsigned short*)d_ws;

    hipMemsetAsync(out, 0, sizeof(float), stream);

    pack_w_kernel<<<24, 256, 0, stream>>>(W1, W2, W3, wsU);

    fused_kernel<<<PHYS_BLOCKS + BDY_BLOCKS, 256, 0, stream>>>(
        xt, x_inlet, U_inlet, x_base, x_top, x_slip,
        W0, b0, W1, b1, W2, b2, W3, b3, W4, b4,
        V0, c0, V1, c1, V2, c2, wsU, out);
}

// Round 4
// 177.917 us; speedup vs baseline: 2.0739x; 1.2728x over previous
//
#include <hip/hip_runtime.h>

#define NTRAIN 32768
#define NBDY   4096
#define PHYS_BLOCKS (NTRAIN / 16)   // 2048
#define BDY_BLOCKS  512             // 32 pts/block, 128 blocks per batch

typedef __bf16 bf16x8 __attribute__((ext_vector_type(8)));
typedef float  f32x4  __attribute__((ext_vector_type(4)));

union FragU { uint4 q; bf16x8 b; __bf16 e[8]; };
union F4 { float4 v; float f[4]; };
union U2 { __bf16 e[4]; uint2 d; };

__device__ __forceinline__ float fast_tanh(float z) {
    float e = __expf(2.0f * z);
    return 1.0f - 2.0f / (e + 1.0f);
}

// ---------------------------------------------------------------------------
// Pack W1..W3 (hi+lo) and V1 (hi) into MFMA fragment order.
// W: idx = ((nt*4 + ks)*64 + lane)*8 + j
//    value = W[ks*32 + (lane>>4)*8 + j][nt*16 + (lane&15)]
//    hi at wsU + l*32768, lo at +16384 (ushort units).
// V1 (64x64): idx = ((nt*2 + ks)*64 + lane)*8 + j at wsU + 98304 (hi only).
// ---------------------------------------------------------------------------
__global__ __launch_bounds__(256) void pack_w_kernel(
    const float* __restrict__ W1, const float* __restrict__ W2,
    const float* __restrict__ W3, const float* __restrict__ V1,
    unsigned short* __restrict__ wsU)
{
    int b = blockIdx.x;
    if (b < 96) {
        int l = b / 32, sub = b % 32;
        const float* W = (l == 0) ? W1 : (l == 1) ? W2 : W3;
        __bf16* hi = (__bf16*)(wsU + l * 32768);
        __bf16* lo = hi + 16384;
        int idx = sub * 512 + threadIdx.x;
        #pragma unroll
        for (int it = 0; it < 2; it++, idx += 256) {
            int j    = idx & 7;
            int lane = (idx >> 3) & 63;
            int ks   = (idx >> 9) & 3;
            int nt   = idx >> 11;
            int k = ks * 32 + (lane >> 4) * 8 + j;
            int n = nt * 16 + (lane & 15);
            float v = W[k * 128 + n];
            __bf16 h = (__bf16)v;
            hi[idx] = h;
            lo[idx] = (__bf16)(v - (float)h);
        }
    } else {
        __bf16* hi = (__bf16*)(wsU + 98304);
        int idx = threadIdx.x;
        #pragma unroll
        for (int it = 0; it < 16; it++, idx += 256) {
            int j    = idx & 7;
            int lane = (idx >> 3) & 63;
            int ks   = (idx >> 9) & 1;
            int nt   = idx >> 10;
            int k = ks * 32 + (lane >> 4) * 8 + j;
            int n = nt * 16 + (lane & 15);
            hi[idx] = (__bf16)V1[k * 64 + n];
        }
    }
}

// ---------------------------------------------------------------------------
// Fused kernel. Blocks [0,2048): physics (16 pts, 5 AD streams).
// Blocks [2048,2560): boundary (32 pts/block).
//
// MFMA role swap: A-operand = W^T fragments (from packed global),
// B-operand = activations (LDS, rows k-contiguous). D: lane holds
// col=point(lane&15), rows=4 consecutive units (q*4+reg) -> transform is
// lane-local AND stores pack 4 consecutive units into one b64.
// Activation LDS: act[row][k], row stride 136 ushorts, bf16 hi/lo planes.
// ---------------------------------------------------------------------------
__global__ __launch_bounds__(256, 3) void fused_kernel(
    const float* __restrict__ xt,
    const float* __restrict__ x_inlet, const float* __restrict__ U_inlet,
    const float* __restrict__ x_base,  const float* __restrict__ x_top,
    const float* __restrict__ x_slip,
    const float* __restrict__ W0, const float* __restrict__ b0,
    const float* __restrict__ W1, const float* __restrict__ b1,
    const float* __restrict__ W2, const float* __restrict__ b2,
    const float* __restrict__ W3, const float* __restrict__ b3,
    const float* __restrict__ W4, const float* __restrict__ b4,
    const float* __restrict__ V0, const float* __restrict__ c0,
    const float* __restrict__ V1, const float* __restrict__ c1,
    const float* __restrict__ V2, const float* __restrict__ c2,
    const unsigned short* __restrict__ wsU,
    float* __restrict__ out)
{
    __shared__ float SM[11856];   // 47424 B -> 3 blocks/CU
    const int t = threadIdx.x;

    if (blockIdx.x < PHYS_BLOCKS) {
        // =================== PHYSICS PATH ===================
        unsigned short* AhU = (unsigned short*)SM;   // 80 x 136 ushorts
        unsigned short* AlU = AhU + 10880;
        float* PART  = SM + 10880;   // 640 floats (also BIAS staging)
        float* BIASF = SM + 10880;   // b1|b2|b3 (384 floats), dead after hidden
        float* OUTF  = SM + 11520;   // 80 x 4
        float* MUV   = SM + 11840;   // 16
        // mu MLP scratch overlaps A region (used before layer 0 writes)
        unsigned short* MUhU  = AhU;          // 16 x 72
        unsigned short* MUlU  = AhU + 1152;
        unsigned short* MU2hU = AhU + 2304;
        unsigned short* MU2lU = AhU + 3456;

        const int p = t >> 4;   // point 0..15
        const int c = t & 15;

        const int ptIdx = blockIdx.x * 16 + p;
        const float2 xy = *(const float2*)(xt + ptIdx * 2);
        const float x = xy.x, y = xy.y;

        // stage hidden-layer biases in LDS (PART region, consumed before L4)
        if (t < 128) {
            BIASF[t]       = b1[t];
            BIASF[128 + t] = b2[t];
            BIASF[256 + t] = b3[t];
        }

        // ---------------- mu MLP layer 1: 2 -> 64 --------------------------
        {
            F4 va, vb, cc;
            va.v = *(const float4*)(V0 + c * 4);
            vb.v = *(const float4*)(V0 + 64 + c * 4);
            cc.v = *(const float4*)(c0 + c * 4);
            U2 ph, pl;
            #pragma unroll
            for (int i = 0; i < 4; i++) {
                float tt = fast_tanh(x * va.f[i] + y * vb.f[i] + cc.f[i]);
                __bf16 h = (__bf16)tt;
                ph.e[i] = h;
                pl.e[i] = (__bf16)(tt - (float)h);
            }
            *(uint2*)(MUhU + p * 72 + c * 4) = ph.d;
            *(uint2*)(MUlU + p * 72 + c * 4) = pl.d;
        }
        __syncthreads();

        const int wv   = t >> 6;
        const int lane = t & 63;
        const int nn   = lane & 15;
        const int q    = lane >> 4;

        // ---------------- mu MLP layer 2: 64 -> 64 via MFMA (2-pass) -------
        {
            f32x4 macc = {0.f, 0.f, 0.f, 0.f};
            #pragma unroll
            for (int ks = 0; ks < 2; ks++) {
                FragU mh, ml, vh;
                int off = nn * 72 + ks * 32 + q * 8;
                mh.q = *(const uint4*)(MUhU + off);
                ml.q = *(const uint4*)(MUlU + off);
                vh.q = *(const uint4*)(wsU + 98304 + (((wv * 2 + ks) * 64 + lane) << 3));
                macc = __builtin_amdgcn_mfma_f32_16x16x32_bf16(vh.b, mh.b, macc, 0, 0, 0);
                macc = __builtin_amdgcn_mfma_f32_16x16x32_bf16(vh.b, ml.b, macc, 0, 0, 0);
            }
            __syncthreads();   // MU reads done before MU2 writes share banks
            int u2base = wv * 16 + q * 4;
            F4 cv; cv.v = *(const float4*)(c1 + u2base);
            U2 ph, pl;
            #pragma unroll
            for (int r = 0; r < 4; r++) {
                float tt = fast_tanh(macc[r] + cv.f[r]);
                __bf16 h = (__bf16)tt;
                ph.e[r] = h;
                pl.e[r] = (__bf16)(tt - (float)h);
            }
            *(uint2*)(MU2hU + nn * 72 + u2base) = ph.d;
            *(uint2*)(MU2lU + nn * 72 + u2base) = pl.d;
        }
        __syncthreads();

        // ---------------- mu MLP layer 3: 64 -> 1 (one wave) ---------------
        if (t < 64) {
            int pt = t & 15, kg = t >> 4;
            float partial = 0.f;
            int base = pt * 72 + kg * 16;
            #pragma unroll
            for (int g = 0; g < 4; g++) {
                U2 hh, ll;
                hh.d = *(const uint2*)(MU2hU + base + g * 4);
                ll.d = *(const uint2*)(MU2lU + base + g * 4);
                F4 w; w.v = *(const float4*)(V2 + kg * 16 + g * 4);
                #pragma unroll
                for (int e = 0; e < 4; e++) {
                    float a = (float)hh.e[e] + (float)ll.e[e];
                    partial += a * w.f[e];
                }
            }
            partial += __shfl_down(partial, 32);
            partial += __shfl_down(partial, 16);
            if (t < 16) {
                float s = partial + c2[0];
                MUV[t] = 0.01f * s * s;
            }
        }
        __syncthreads();

        // ---------------- layer 0: 2 -> 128, 5 streams ---------------------
        {
            float vals[5][8];
            #pragma unroll
            for (int j = 0; j < 8; j++) {
                int u = c * 8 + j;
                float w0 = W0[u], w1 = W0[128 + u];
                float zv = x * w0 + y * w1 + b0[u];
                float tt = fast_tanh(zv);
                float s2 = 1.f - tt * tt;
                float m2 = -2.f * tt * s2;
                vals[0][j] = tt;
                vals[1][j] = s2 * w0;
                vals[2][j] = s2 * w1;
                vals[3][j] = m2 * w0 * w0;
                vals[4][j] = m2 * w1 * w1;
            }
            #pragma unroll
            for (int s = 0; s < 5; s++) {
                FragU fh, fl;
                #pragma unroll
                for (int j = 0; j < 8; j++) {
                    __bf16 h = (__bf16)vals[s][j];
                    fh.e[j] = h;
                    fl.e[j] = (__bf16)(vals[s][j] - (float)h);
                }
                int off = (s * 16 + p) * 136 + c * 8;
                *(uint4*)(AhU + off) = fh.q;
                *(uint4*)(AlU + off) = fl.q;
            }
        }
        __syncthreads();

        // ---------------- hidden layers 1..3 via MFMA (W as A-operand) -----
        #pragma unroll 1
        for (int l = 0; l < 3; l++) {
            const unsigned short* WpL = wsU + l * 32768;
            f32x4 acc[2][5];
            #pragma unroll
            for (int i = 0; i < 2; i++)
                #pragma unroll
                for (int s = 0; s < 5; s++) {
                    acc[i][s][0] = 0.f; acc[i][s][1] = 0.f;
                    acc[i][s][2] = 0.f; acc[i][s][3] = 0.f;
                }
            #pragma unroll
            for (int ks = 0; ks < 4; ks++) {
                FragU bh[5], bl[5];
                #pragma unroll
                for (int s = 0; s < 5; s++) {
                    int off = (s * 16 + nn) * 136 + ks * 32 + q * 8;
                    bh[s].q = *(const uint4*)(AhU + off);
                    bl[s].q = *(const uint4*)(AlU + off);
                }
                FragU wh[2], wl[2];
                #pragma unroll
                for (int i = 0; i < 2; i++) {
                    const unsigned short* base =
                        WpL + ((((2 * wv + i) * 4 + ks) * 64 + lane) << 3);
                    wh[i].q = *(const uint4*)base;
                    wl[i].q = *(const uint4*)(base + 16384);
                }
                #pragma unroll
                for (int i = 0; i < 2; i++)
                    #pragma unroll
                    for (int s = 0; s < 5; s++) {
                        acc[i][s] = __builtin_amdgcn_mfma_f32_16x16x32_bf16(
                            wh[i].b, bh[s].b, acc[i][s], 0, 0, 0);
                        acc[i][s] = __builtin_amdgcn_mfma_f32_16x16x32_bf16(
                            wh[i].b, bl[s].b, acc[i][s], 0, 0, 0);
                        acc[i][s] = __builtin_amdgcn_mfma_f32_16x16x32_bf16(
                            wl[i].b, bh[s].b, acc[i][s], 0, 0, 0);
                    }
            }
            __syncthreads();   // all A reads done before overwrite
            #pragma unroll
            for (int i = 0; i < 2; i++) {
                int ubase = (2 * wv + i) * 16 + q * 4;
                F4 bv; bv.v = *(const float4*)&BIASF[l * 128 + ubase];
                float vals[5][4];
                #pragma unroll
                for (int r = 0; r < 4; r++) {
                    float z   = acc[i][0][r] + bv.f[r];
                    float zx  = acc[i][1][r], zy  = acc[i][2][r];
                    float zxx = acc[i][3][r], zyy = acc[i][4][r];
                    float tt = fast_tanh(z);
                    float s2 = 1.f - tt * tt;
                    float m2 = -2.f * tt * s2;
                    vals[0][r] = tt;
                    vals[1][r] = s2 * zx;
                    vals[2][r] = s2 * zy;
                    vals[3][r] = s2 * zxx + m2 * zx * zx;
                    vals[4][r] = s2 * zyy + m2 * zy * zy;
                }
                #pragma unroll
                for (int s = 0; s < 5; s++) {
                    U2 ph, pl;
                    #pragma unroll
                    for (int r = 0; r < 4; r++) {
                        __bf16 h = (__bf16)vals[s][r];
                        ph.e[r] = h;
                        pl.e[r] = (__bf16)(vals[s][r] - (float)h);
                    }
                    int off = (s * 16 + nn) * 136 + ubase;
                    *(uint2*)(AhU + off) = ph.d;
                    *(uint2*)(AlU + off) = pl.d;
                }
            }
            __syncthreads();
        }

        // ---------------- layer 4: 128 -> 4 (linear), k-split 2 ------------
        if (t < 160) {
            int r    = t >> 1;   // row 0..79 = s*16 + p
            int half = t & 1;
            float a0 = 0.f, a1 = 0.f, a2 = 0.f, a3 = 0.f;
            if (half == 0 && r < 16) { a0 = b4[0]; a1 = b4[1]; a2 = b4[2]; a3 = b4[3]; }
            const int abase = r * 136 + half * 64;
            const float* W4h = W4 + half * 256;
            #pragma unroll
            for (int k0 = 0; k0 < 64; k0 += 8) {
                FragU qh, ql;
                qh.q = *(const uint4*)(AhU + abase + k0);
                ql.q = *(const uint4*)(AlU + abase + k0);
                #pragma unroll
                for (int j = 0; j < 8; j++) {
                    float a = (float)qh.e[j] + (float)ql.e[j];
                    float4 w = *(const float4*)(W4h + (k0 + j) * 4);
                    a0 += a * w.x; a1 += a * w.y; a2 += a * w.z; a3 += a * w.w;
                }
            }
            *(float4*)&PART[t * 4] = make_float4(a0, a1, a2, a3);
        }
        __syncthreads();
        if (t < 80) {
            float4 u0 = *(float4*)&PART[(2 * t) * 4];
            float4 u1 = *(float4*)&PART[(2 * t + 1) * 4];
            *(float4*)&OUTF[t * 4] =
                make_float4(u0.x + u1.x, u0.y + u1.y, u0.z + u1.z, u0.w + u1.w);
        }
        __syncthreads();

        // ---------------- per-point residual + reduction -------------------
        float contrib = 0.f;
        if (t < 16) {
            const int pp = t;
            const float* V   = &OUTF[(0  + pp) * 4];
            const float* DX  = &OUTF[(16 + pp) * 4];
            const float* DY  = &OUTF[(32 + pp) * 4];
            const float* SXX = &OUTF[(48 + pp) * 4];
            const float* SYY = &OUTF[(64 + pp) * 4];
            float r = V[0],  P = V[1],  u = V[2],  v = V[3];
            float rx = DX[0], Px = DX[1], ux = DX[2], vx = DX[3];
            float ry = DY[0], Py = DY[1], uy = DY[2], vy = DY[3];
            float rxx = SXX[0], Pxx = SXX[1], uxx = SXX[2], vxx = SXX[3];
            float ryy = SYY[0], Pyy = SYY[1], uyy = SYY[2], vyy = SYY[3];
            const float GI = 2.5f;  // 1/(gamma-1)

            float q2  = u * u + v * v;
            float E  = P * GI + 0.5f * r * q2;
            float Ex = Px * GI + 0.5f * rx * q2 + r * (u * ux + v * vx);
            float Ey = Py * GI + 0.5f * ry * q2 + r * (u * uy + v * vy);
            float EpP = E + P;

            float f1x = rx * u + r * ux;
            float f2x = rx * u * u + 2.f * r * u * ux + Px;
            float f3x = rx * u * v + r * ux * v + r * u * vx;
            float f4x = ux * EpP + u * (Ex + Px);

            float g1y = ry * v + r * vy;
            float g2y = ry * u * v + r * uy * v + r * u * vy;
            float g3y = ry * v * v + 2.f * r * v * vy + Py;
            float g4y = vy * EpP + v * (Ey + Py);

            float qx  = 2.f * (u * ux + v * vx);
            float qy  = 2.f * (u * uy + v * vy);
            float qxx = 2.f * (ux * ux + u * uxx + vx * vx + v * vxx);
            float qyy = 2.f * (uy * uy + u * uyy + vy * vy + v * vyy);

            float U1s = rxx + ryy;
            float U2s = (rxx * u + 2.f * rx * ux + r * uxx)
                      + (ryy * u + 2.f * ry * uy + r * uyy);
            float U3s = (rxx * v + 2.f * rx * vx + r * vxx)
                      + (ryy * v + 2.f * ry * vy + r * vyy);
            float U4s = (Pxx + Pyy) * GI
                      + 0.5f * (rxx * q2 + 2.f * rx * qx + r * qxx
                              + ryy * q2 + 2.f * ry * qy + r * qyy);

            float mu = MUV[pp];
            float r1 = f1x + g1y - mu * U1s;
            float r2 = f2x + g2y - mu * U2s;
            float r3 = f3x + g3y - mu * U3s;
            float r4 = f4x + g4y - mu * U4s;

            contrib = (r1 * r1 + r2 * r2 + r3 * r3 + r4 * r4 + 0.1f * mu * mu)
                      * (1.0f / (float)NTRAIN);
        }
        if (t < 64) {
            contrib += __shfl_down(contrib, 32);
            contrib += __shfl_down(contrib, 16);
            contrib += __shfl_down(contrib, 8);
            contrib += __shfl_down(contrib, 4);
            contrib += __shfl_down(contrib, 2);
            contrib += __shfl_down(contrib, 1);
            if (t == 0) atomicAdd(out, contrib);
        }
    } else {
        // =================== BOUNDARY PATH (MFMA, 32 pts/block) ============
        unsigned short* ShU = (unsigned short*)SM;   // 32 x 136
        unsigned short* SlU = ShU + 4352;
        float* PBf   = SM + 4352;   // 8 x 32 x 4 floats
        float* BIASB = SM + 5376;   // 384 floats

        const int bb    = blockIdx.x - PHYS_BLOCKS;
        const int batch = bb >> 7;  // 0..3 (128 blocks each)
        const int lb    = bb & 127;
        const float* xs = (batch == 0) ? x_inlet
                        : (batch == 1) ? x_base
                        : (batch == 2) ? x_top : x_slip;
        const int base_pt = lb * 32;

        // ---- layer 0: 2 -> 128 + bias staging ----
        {
            int p2 = t & 31, ug = t >> 5;
            float2 xy = *(const float2*)(xs + (base_pt + p2) * 2);
            float x = xy.x, y = xy.y;
            #pragma unroll
            for (int g = 0; g < 4; g++) {
                int u0 = ug * 16 + g * 4;
                F4 wa, wb, bbv;
                wa.v  = *(const float4*)(W0 + u0);
                wb.v  = *(const float4*)(W0 + 128 + u0);
                bbv.v = *(const float4*)(b0 + u0);
                U2 ph, pl;
                #pragma unroll
                for (int e = 0; e < 4; e++) {
                    float tt = fast_tanh(x * wa.f[e] + y * wb.f[e] + bbv.f[e]);
                    __bf16 h = (__bf16)tt;
                    ph.e[e] = h;
                    pl.e[e] = (__bf16)(tt - (float)h);
                }
                *(uint2*)(ShU + p2 * 136 + u0) = ph.d;
                *(uint2*)(SlU + p2 * 136 + u0) = pl.d;
            }
            if (t < 128) {
                BIASB[t]       = b1[t];
                BIASB[128 + t] = b2[t];
                BIASB[256 + t] = b3[t];
            }
        }
        __syncthreads();

        const int wv   = t >> 6;
        const int lane = t & 63;
        const int nn   = lane & 15;
        const int q    = lane >> 4;

        // ---- hidden layers 1..3 via MFMA ----
        #pragma unroll 1
        for (int l = 0; l < 3; l++) {
            const unsigned short* WpL = wsU + l * 32768;
            f32x4 acc[2][2];
            #pragma unroll
            for (int i = 0; i < 2; i++)
                #pragma unroll
                for (int n = 0; n < 2; n++) {
                    acc[i][n][0] = 0.f; acc[i][n][1] = 0.f;
                    acc[i][n][2] = 0.f; acc[i][n][3] = 0.f;
                }
            #pragma unroll
            for (int ks = 0; ks < 4; ks++) {
                FragU bh[2], bl[2];
                #pragma unroll
                for (int n = 0; n < 2; n++) {
                    int off = (n * 16 + nn) * 136 + ks * 32 + q * 8;
                    bh[n].q = *(const uint4*)(ShU + off);
                    bl[n].q = *(const uint4*)(SlU + off);
                }
                FragU wh[2], wl[2];
                #pragma unroll
                for (int i = 0; i < 2; i++) {
                    const unsigned short* base =
                        WpL + ((((2 * wv + i) * 4 + ks) * 64 + lane) << 3);
                    wh[i].q = *(const uint4*)base;
                    wl[i].q = *(const uint4*)(base + 16384);
                }
                #pragma unroll
                for (int i = 0; i < 2; i++)
                    #pragma unroll
                    for (int n = 0; n < 2; n++) {
                        acc[i][n] = __builtin_amdgcn_mfma_f32_16x16x32_bf16(
                            wh[i].b, bh[n].b, acc[i][n], 0, 0, 0);
                        acc[i][n] = __builtin_amdgcn_mfma_f32_16x16x32_bf16(
                            wh[i].b, bl[n].b, acc[i][n], 0, 0, 0);
                        acc[i][n] = __builtin_amdgcn_mfma_f32_16x16x32_bf16(
                            wl[i].b, bh[n].b, acc[i][n], 0, 0, 0);
                    }
            }
            __syncthreads();
            #pragma unroll
            for (int i = 0; i < 2; i++) {
                int ubase = (2 * wv + i) * 16 + q * 4;
                F4 bv; bv.v = *(const float4*)&BIASB[l * 128 + ubase];
                #pragma unroll
                for (int n = 0; n < 2; n++) {
                    U2 ph, pl;
                    #pragma unroll
                    for (int r = 0; r < 4; r++) {
                        float tt = fast_tanh(acc[i][n][r] + bv.f[r]);
                        __bf16 h = (__bf16)tt;
                        ph.e[r] = h;
                        pl.e[r] = (__bf16)(tt - (float)h);
                    }
                    int off = (n * 16 + nn) * 136 + ubase;
                    *(uint2*)(ShU + off) = ph.d;
                    *(uint2*)(SlU + off) = pl.d;
                }
            }
            __syncthreads();
        }

        // ---- layer 4: 128 -> 4, k-split 8 ----
        {
            int p2 = t & 31, kg = t >> 5;
            float a0 = 0.f, a1 = 0.f, a2 = 0.f, a3 = 0.f;
            if (kg == 0) { a0 = b4[0]; a1 = b4[1]; a2 = b4[2]; a3 = b4[3]; }
            int abase = p2 * 136 + kg * 16;
            #pragma unroll
            for (int g = 0; g < 4; g++) {
                U2 hh, ll;
                hh.d = *(const uint2*)(ShU + abase + g * 4);
                ll.d = *(const uint2*)(SlU + abase + g * 4);
                #pragma unroll
                for (int e = 0; e < 4; e++) {
                    float a = (float)hh.e[e] + (float)ll.e[e];
                    float4 w = *(const float4*)(W4 + (kg * 16 + g * 4 + e) * 4);
                    a0 += a * w.x; a1 += a * w.y; a2 += a * w.z; a3 += a * w.w;
                }
            }
            *(float4*)&PBf[(kg * 32 + p2) * 4] = make_float4(a0, a1, a2, a3);
        }
        __syncthreads();

        float contrib = 0.f;
        if (t < 32) {
            float o0 = 0.f, o1 = 0.f, o2 = 0.f, o3 = 0.f;
            #pragma unroll
            for (int kg = 0; kg < 8; kg++) {
                float4 pv = *(const float4*)&PBf[(kg * 32 + t) * 4];
                o0 += pv.x; o1 += pv.y; o2 += pv.z; o3 += pv.w;
            }
            float l;
            if (batch == 0) {
                float4 Ui = *(const float4*)(U_inlet + (base_pt + t) * 4);
                float d0 = o0 - Ui.x, d1 = o1 - Ui.y, d2 = o2 - Ui.z, d3 = o3 - Ui.w;
                l = d0 * d0 + d1 * d1 + d2 * d2 + d3 * d3;
            } else if (batch == 3) {
                const float sa = -0.17364817766693033f;  // sin(-pi/18)
                const float ca =  0.9848077530122080f;   // cos(-pi/18)
                float d = -o2 * sa + o3 * ca;
                l = d * d;
            } else {
                l = o3 * o3;
            }
            contrib = 10.0f * l * (1.0f / (float)NBDY);
        }
        if (t < 64) {
            contrib += __shfl_down(contrib, 16);
            contrib += __shfl_down(contrib, 8);
            contrib += __shfl_down(contrib, 4);
            contrib += __shfl_down(contrib, 2);
            contrib += __shfl_down(contrib, 1);
            if (t == 0) atomicAdd(out, contrib);
        }
    }
}

extern "C" void kernel_launch(void* const* d_in, const int* in_sizes, int n_in,
                              void* d_out, int out_size, void* d_ws, size_t ws_size,
                              hipStream_t stream) {
    const float* xt      = (const float*)d_in[0];
    const float* x_inlet = (const float*)d_in[1];
    const float* U_inlet = (const float*)d_in[2];
    const float* x_base  = (const float*)d_in[3];
    const float* x_top   = (const float*)d_in[4];
    const float* x_slip  = (const float*)d_in[5];
    const float* W0 = (const float*)d_in[6];
    const float* b0 = (const float*)d_in[7];
    const float* W1 = (const float*)d_in[8];
    const float* b1 = (const float*)d_in[9];
    const float* W2 = (const float*)d_in[10];
    const float* b2 = (const float*)d_in[11];
    const float* W3 = (const float*)d_in[12];
    const float* b3 = (const float*)d_in[13];
    const float* W4 = (const float*)d_in[14];
    const float* b4 = (const float*)d_in[15];
    const float* V0 = (const float*)d_in[16];
    const float* c0 = (const float*)d_in[17];
    const float* V1 = (const float*)d_in[18];
    const float* c1 = (const float*)d_in[19];
    const float* V2 = (const float*)d_in[20];
    const float* c2 = (const float*)d_in[21];
    float* out = (float*)d_out;
    unsigned short* wsU = (unsigned short*)d_ws;

    hipMemsetAsync(out, 0, sizeof(float), stream);

    pack_w_kernel<<<97, 256, 0, stream>>>(W1, W2, W3, V1, wsU);

    fused_kernel<<<PHYS_BLOCKS + BDY_BLOCKS, 256, 0, stream>>>(
        xt, x_inlet, U_inlet, x_base, x_top, x_slip,
        W0, b0, W1, b1, W2, b2, W3, b3, W4, b4,
        V0, c0, V1, c1, V2, c2, wsU, out);
}

// Round 5
// 169.410 us; speedup vs baseline: 2.1781x; 1.0502x over previous
//
#include <hip/hip_runtime.h>

#define NTRAIN 32768
#define NBDY   4096
#define PHYS_BLOCKS (NTRAIN / 16)   // 2048
#define BDY_BLOCKS  512             // 32 pts/block, 128 blocks per batch

typedef _Float16 f16x8 __attribute__((ext_vector_type(8)));
typedef float    f32x4 __attribute__((ext_vector_type(4)));

union FragU { uint4 q; f16x8 b; _Float16 e[8]; };
union F4  { float4 v; float f[4]; };
union U2h { _Float16 e[4]; uint2 d; };

__device__ __forceinline__ float fast_tanh(float z) {
    float e = __expf(2.0f * z);
    return 1.0f - 2.0f / (e + 1.0f);
}

// ---------------------------------------------------------------------------
// Pack W1..W3 (fp16 hi+lo) and V1 (fp16) into MFMA A-fragment order.
// Out uint4 index u4 = (nt*4 + ks)*64 + lane holds j=0..7:
//   value = W[ks*32 + (lane>>4)*8 + j][nt*16 + (lane&15)]
// hi at wsU + l*32768, lo at +16384 (ushort units). V1 at wsU + 98304.
// Reads: per j, 64 lanes hit 4 rows x 16 consecutive cols (64B segments).
// Writes: fully contiguous uint4. Also zeroes out[0] (replaces memset node).
// ---------------------------------------------------------------------------
__global__ __launch_bounds__(256) void pack_w_kernel(
    const float* __restrict__ W1, const float* __restrict__ W2,
    const float* __restrict__ W3, const float* __restrict__ V1,
    unsigned short* __restrict__ wsU, float* __restrict__ out)
{
    int b = blockIdx.x;
    if (b < 3) {
        const float* W = (b == 0) ? W1 : (b == 1) ? W2 : W3;
        _Float16* hi = (_Float16*)(wsU + b * 32768);
        _Float16* lo = hi + 16384;
        int u4 = threadIdx.x;
        #pragma unroll
        for (int it = 0; it < 8; it++, u4 += 256) {
            int lane = u4 & 63, ks = (u4 >> 6) & 3, nt = u4 >> 8;
            int kb = ks * 32 + (lane >> 4) * 8;
            int n  = nt * 16 + (lane & 15);
            FragU fh, fl;
            #pragma unroll
            for (int j = 0; j < 8; j++) {
                float v = W[(kb + j) * 128 + n];
                _Float16 h = (_Float16)v;
                fh.e[j] = h;
                fl.e[j] = (_Float16)(v - (float)h);
            }
            *(uint4*)(hi + u4 * 8) = fh.q;
            *(uint4*)(lo + u4 * 8) = fl.q;
        }
    } else {
        _Float16* hi = (_Float16*)(wsU + 98304);
        int u4 = threadIdx.x;
        #pragma unroll
        for (int it = 0; it < 2; it++, u4 += 256) {
            int lane = u4 & 63, ks = (u4 >> 6) & 1, nt = u4 >> 7;
            int kb = ks * 32 + (lane >> 4) * 8;
            int n  = nt * 16 + (lane & 15);
            FragU fh;
            #pragma unroll
            for (int j = 0; j < 8; j++)
                fh.e[j] = (_Float16)V1[(kb + j) * 64 + n];
            *(uint4*)(hi + u4 * 8) = fh.q;
        }
        if (threadIdx.x == 0) out[0] = 0.f;
    }
}

// ---------------------------------------------------------------------------
// Fused kernel. Blocks [0,2048): physics (16 pts, 5 AD streams).
// Blocks [2048,2560): boundary (32 pts/block).
//
// fp16 2-pass emulation: A-operand = W^T fragments hi+lo fp16 (global,
// packed), B-operand = activations single fp16 plane (LDS, k-contiguous,
// row stride 136 ushorts). acc = Wh*a + Wl*a; activation rounding 2^-12.
// D layout: lane holds col=point(lane&15), rows=4 consecutive units
// (q*4+reg) -> lane-local transform, b64-packed stores.
// ---------------------------------------------------------------------------
__global__ __launch_bounds__(256, 5) void fused_kernel(
    const float* __restrict__ xt,
    const float* __restrict__ x_inlet, const float* __restrict__ U_inlet,
    const float* __restrict__ x_base,  const float* __restrict__ x_top,
    const float* __restrict__ x_slip,
    const float* __restrict__ W0, const float* __restrict__ b0,
    const float* __restrict__ W1, const float* __restrict__ b1,
    const float* __restrict__ W2, const float* __restrict__ b2,
    const float* __restrict__ W3, const float* __restrict__ b3,
    const float* __restrict__ W4, const float* __restrict__ b4,
    const float* __restrict__ V0, const float* __restrict__ c0,
    const float* __restrict__ V1, const float* __restrict__ c1,
    const float* __restrict__ V2, const float* __restrict__ c2,
    const unsigned short* __restrict__ wsU,
    float* __restrict__ out)
{
    __shared__ float SM[6416];   // 25664 B -> 5+ blocks/CU
    const int t = threadIdx.x;

    if (blockIdx.x < PHYS_BLOCKS) {
        // =================== PHYSICS PATH ===================
        unsigned short* AhU = (unsigned short*)SM;   // 80 x 136 ushorts
        float* PART  = SM + 5440;   // 640 floats (layer-4 partials)
        float* BIASF = SM + 5440;   // b1|b2|b3 (384 floats), dead before L4
        float* OUTF  = SM + 6080;   // 80 x 4
        float* MUV   = SM + 6400;   // 16
        // mu MLP scratch overlaps A region (consumed before layer 0 writes)
        unsigned short* MUhU  = AhU;          // 16 x 72
        unsigned short* MU2hU = AhU + 1152;   // 16 x 72

        const int p = t >> 4;   // point 0..15
        const int c = t & 15;

        const int ptIdx = blockIdx.x * 16 + p;
        const float2 xy = *(const float2*)(xt + ptIdx * 2);
        const float x = xy.x, y = xy.y;

        // stage hidden-layer biases (PART region, consumed before L4)
        if (t < 128) {
            BIASF[t]       = b1[t];
            BIASF[128 + t] = b2[t];
            BIASF[256 + t] = b3[t];
        }

        // ---------------- mu MLP layer 1: 2 -> 64 --------------------------
        {
            F4 va, vb, cc;
            va.v = *(const float4*)(V0 + c * 4);
            vb.v = *(const float4*)(V0 + 64 + c * 4);
            cc.v = *(const float4*)(c0 + c * 4);
            U2h ph;
            #pragma unroll
            for (int i = 0; i < 4; i++)
                ph.e[i] = (_Float16)fast_tanh(x * va.f[i] + y * vb.f[i] + cc.f[i]);
            *(uint2*)(MUhU + p * 72 + c * 4) = ph.d;
        }
        __syncthreads();

        const int wv   = t >> 6;
        const int lane = t & 63;
        const int nn   = lane & 15;
        const int q    = lane >> 4;

        // ---------------- mu MLP layer 2: 64 -> 64 via MFMA (1-pass) -------
        {
            f32x4 macc = {0.f, 0.f, 0.f, 0.f};
            #pragma unroll
            for (int ks = 0; ks < 2; ks++) {
                FragU mh, vh;
                mh.q = *(const uint4*)(MUhU + nn * 72 + ks * 32 + q * 8);
                vh.q = *(const uint4*)(wsU + 98304 + (((wv * 2 + ks) * 64 + lane) << 3));
                macc = __builtin_amdgcn_mfma_f32_16x16x32_f16(vh.b, mh.b, macc, 0, 0, 0);
            }
            int u2base = wv * 16 + q * 4;
            F4 cv; cv.v = *(const float4*)(c1 + u2base);
            U2h ph;
            #pragma unroll
            for (int r = 0; r < 4; r++)
                ph.e[r] = (_Float16)fast_tanh(macc[r] + cv.f[r]);
            *(uint2*)(MU2hU + nn * 72 + u2base) = ph.d;
        }
        __syncthreads();

        // ---------------- mu MLP layer 3: 64 -> 1 (one wave) ---------------
        if (t < 64) {
            int pt = t & 15, kg = t >> 4;
            float partial = 0.f;
            int base = pt * 72 + kg * 16;
            #pragma unroll
            for (int g = 0; g < 4; g++) {
                U2h hh;
                hh.d = *(const uint2*)(MU2hU + base + g * 4);
                F4 w; w.v = *(const float4*)(V2 + kg * 16 + g * 4);
                #pragma unroll
                for (int e = 0; e < 4; e++)
                    partial += (float)hh.e[e] * w.f[e];
            }
            partial += __shfl_down(partial, 32);
            partial += __shfl_down(partial, 16);
            if (t < 16) {
                float s = partial + c2[0];
                MUV[t] = 0.01f * s * s;
            }
        }
        __syncthreads();

        // ---------------- layer 0: 2 -> 128, 5 streams ---------------------
        {
            float vals[5][8];
            #pragma unroll
            for (int j = 0; j < 8; j++) {
                int u = c * 8 + j;
                float w0 = W0[u], w1 = W0[128 + u];
                float zv = x * w0 + y * w1 + b0[u];
                float tt = fast_tanh(zv);
                float s2 = 1.f - tt * tt;
                float m2 = -2.f * tt * s2;
                vals[0][j] = tt;
                vals[1][j] = s2 * w0;
                vals[2][j] = s2 * w1;
                vals[3][j] = m2 * w0 * w0;
                vals[4][j] = m2 * w1 * w1;
            }
            #pragma unroll
            for (int s = 0; s < 5; s++) {
                FragU fh;
                #pragma unroll
                for (int j = 0; j < 8; j++) fh.e[j] = (_Float16)vals[s][j];
                *(uint4*)(AhU + (s * 16 + p) * 136 + c * 8) = fh.q;
            }
        }
        __syncthreads();

        // ---------------- hidden layers 1..3 via MFMA (W hi/lo 2-pass) -----
        #pragma unroll 1
        for (int l = 0; l < 3; l++) {
            const unsigned short* WpL = wsU + l * 32768;
            f32x4 acc[2][5];
            #pragma unroll
            for (int i = 0; i < 2; i++)
                #pragma unroll
                for (int s = 0; s < 5; s++) {
                    acc[i][s][0] = 0.f; acc[i][s][1] = 0.f;
                    acc[i][s][2] = 0.f; acc[i][s][3] = 0.f;
                }
            #pragma unroll
            for (int ks = 0; ks < 4; ks++) {
                FragU bh[5];
                #pragma unroll
                for (int s = 0; s < 5; s++)
                    bh[s].q = *(const uint4*)(AhU + (s * 16 + nn) * 136 + ks * 32 + q * 8);
                FragU wh[2], wl[2];
                #pragma unroll
                for (int i = 0; i < 2; i++) {
                    const unsigned short* base =
                        WpL + ((((2 * wv + i) * 4 + ks) * 64 + lane) << 3);
                    wh[i].q = *(const uint4*)base;
                    wl[i].q = *(const uint4*)(base + 16384);
                }
                #pragma unroll
                for (int i = 0; i < 2; i++)
                    #pragma unroll
                    for (int s = 0; s < 5; s++) {
                        acc[i][s] = __builtin_amdgcn_mfma_f32_16x16x32_f16(
                            wh[i].b, bh[s].b, acc[i][s], 0, 0, 0);
                        acc[i][s] = __builtin_amdgcn_mfma_f32_16x16x32_f16(
                            wl[i].b, bh[s].b, acc[i][s], 0, 0, 0);
                    }
            }
            __syncthreads();   // all A reads done before overwrite
            #pragma unroll
            for (int i = 0; i < 2; i++) {
                int ubase = (2 * wv + i) * 16 + q * 4;
                F4 bv; bv.v = *(const float4*)&BIASF[l * 128 + ubase];
                float vals[5][4];
                #pragma unroll
                for (int r = 0; r < 4; r++) {
                    float z   = acc[i][0][r] + bv.f[r];
                    float zx  = acc[i][1][r], zy  = acc[i][2][r];
                    float zxx = acc[i][3][r], zyy = acc[i][4][r];
                    float tt = fast_tanh(z);
                    float s2 = 1.f - tt * tt;
                    float m2 = -2.f * tt * s2;
                    vals[0][r] = tt;
                    vals[1][r] = s2 * zx;
                    vals[2][r] = s2 * zy;
                    vals[3][r] = s2 * zxx + m2 * zx * zx;
                    vals[4][r] = s2 * zyy + m2 * zy * zy;
                }
                #pragma unroll
                for (int s = 0; s < 5; s++) {
                    U2h ph;
                    #pragma unroll
                    for (int r = 0; r < 4; r++) ph.e[r] = (_Float16)vals[s][r];
                    *(uint2*)(AhU + (s * 16 + nn) * 136 + ubase) = ph.d;
                }
            }
            __syncthreads();
        }

        // ---------------- layer 4: 128 -> 4 (linear), k-split 2 ------------
        if (t < 160) {
            int r    = t >> 1;   // row 0..79 = s*16 + p
            int half = t & 1;
            float a0 = 0.f, a1 = 0.f, a2 = 0.f, a3 = 0.f;
            if (half == 0 && r < 16) { a0 = b4[0]; a1 = b4[1]; a2 = b4[2]; a3 = b4[3]; }
            const int abase = r * 136 + half * 64;
            const float* W4h = W4 + half * 256;
            #pragma unroll
            for (int k0 = 0; k0 < 64; k0 += 8) {
                FragU qh;
                qh.q = *(const uint4*)(AhU + abase + k0);
                #pragma unroll
                for (int j = 0; j < 8; j++) {
                    float a = (float)qh.e[j];
                    float4 w = *(const float4*)(W4h + (k0 + j) * 4);
                    a0 += a * w.x; a1 += a * w.y; a2 += a * w.z; a3 += a * w.w;
                }
            }
            *(float4*)&PART[t * 4] = make_float4(a0, a1, a2, a3);
        }
        __syncthreads();
        if (t < 80) {
            float4 u0 = *(float4*)&PART[(2 * t) * 4];
            float4 u1 = *(float4*)&PART[(2 * t + 1) * 4];
            *(float4*)&OUTF[t * 4] =
                make_float4(u0.x + u1.x, u0.y + u1.y, u0.z + u1.z, u0.w + u1.w);
        }
        __syncthreads();

        // ---------------- per-point residual + reduction -------------------
        float contrib = 0.f;
        if (t < 16) {
            const int pp = t;
            const float* V   = &OUTF[(0  + pp) * 4];
            const float* DX  = &OUTF[(16 + pp) * 4];
            const float* DY  = &OUTF[(32 + pp) * 4];
            const float* SXX = &OUTF[(48 + pp) * 4];
            const float* SYY = &OUTF[(64 + pp) * 4];
            float r = V[0],  P = V[1],  u = V[2],  v = V[3];
            float rx = DX[0], Px = DX[1], ux = DX[2], vx = DX[3];
            float ry = DY[0], Py = DY[1], uy = DY[2], vy = DY[3];
            float rxx = SXX[0], Pxx = SXX[1], uxx = SXX[2], vxx = SXX[3];
            float ryy = SYY[0], Pyy = SYY[1], uyy = SYY[2], vyy = SYY[3];
            const float GI = 2.5f;  // 1/(gamma-1)

            float q2  = u * u + v * v;
            float E  = P * GI + 0.5f * r * q2;
            float Ex = Px * GI + 0.5f * rx * q2 + r * (u * ux + v * vx);
            float Ey = Py * GI + 0.5f * ry * q2 + r * (u * uy + v * vy);
            float EpP = E + P;

            float f1x = rx * u + r * ux;
            float f2x = rx * u * u + 2.f * r * u * ux + Px;
            float f3x = rx * u * v + r * ux * v + r * u * vx;
            float f4x = ux * EpP + u * (Ex + Px);

            float g1y = ry * v + r * vy;
            float g2y = ry * u * v + r * uy * v + r * u * vy;
            float g3y = ry * v * v + 2.f * r * v * vy + Py;
            float g4y = vy * EpP + v * (Ey + Py);

            float qx  = 2.f * (u * ux + v * vx);
            float qy  = 2.f * (u * uy + v * vy);
            float qxx = 2.f * (ux * ux + u * uxx + vx * vx + v * vxx);
            float qyy = 2.f * (uy * uy + u * uyy + vy * vy + v * vyy);

            float U1s = rxx + ryy;
            float U2s = (rxx * u + 2.f * rx * ux + r * uxx)
                      + (ryy * u + 2.f * ry * uy + r * uyy);
            float U3s = (rxx * v + 2.f * rx * vx + r * vxx)
                      + (ryy * v + 2.f * ry * vy + r * vyy);
            float U4s = (Pxx + Pyy) * GI
                      + 0.5f * (rxx * q2 + 2.f * rx * qx + r * qxx
                              + ryy * q2 + 2.f * ry * qy + r * qyy);

            float mu = MUV[pp];
            float r1 = f1x + g1y - mu * U1s;
            float r2 = f2x + g2y - mu * U2s;
            float r3 = f3x + g3y - mu * U3s;
            float r4 = f4x + g4y - mu * U4s;

            contrib = (r1 * r1 + r2 * r2 + r3 * r3 + r4 * r4 + 0.1f * mu * mu)
                      * (1.0f / (float)NTRAIN);
        }
        if (t < 64) {
            contrib += __shfl_down(contrib, 32);
            contrib += __shfl_down(contrib, 16);
            contrib += __shfl_down(contrib, 8);
            contrib += __shfl_down(contrib, 4);
            contrib += __shfl_down(contrib, 2);
            contrib += __shfl_down(contrib, 1);
            if (t == 0) atomicAdd(out, contrib);
        }
    } else {
        // =================== BOUNDARY PATH (MFMA, 32 pts/block) ============
        unsigned short* ShU = (unsigned short*)SM;   // 32 x 136
        float* PBf   = SM + 2176;   // 8 x 32 x 4 floats
        float* BIASB = SM + 3200;   // 384 floats

        const int bb    = blockIdx.x - PHYS_BLOCKS;
        const int batch = bb >> 7;  // 0..3 (128 blocks each)
        const int lb    = bb & 127;
        const float* xs = (batch == 0) ? x_inlet
                        : (batch == 1) ? x_base
                        : (batch == 2) ? x_top : x_slip;
        const int base_pt = lb * 32;

        // ---- layer 0: 2 -> 128 + bias staging ----
        {
            int p2 = t & 31, ug = t >> 5;
            float2 xy = *(const float2*)(xs + (base_pt + p2) * 2);
            float x = xy.x, y = xy.y;
            #pragma unroll
            for (int g = 0; g < 4; g++) {
                int u0 = ug * 16 + g * 4;
                F4 wa, wb, bbv;
                wa.v  = *(const float4*)(W0 + u0);
                wb.v  = *(const float4*)(W0 + 128 + u0);
                bbv.v = *(const float4*)(b0 + u0);
                U2h ph;
                #pragma unroll
                for (int e = 0; e < 4; e++)
                    ph.e[e] = (_Float16)fast_tanh(x * wa.f[e] + y * wb.f[e] + bbv.f[e]);
                *(uint2*)(ShU + p2 * 136 + u0) = ph.d;
            }
            if (t < 128) {
                BIASB[t]       = b1[t];
                BIASB[128 + t] = b2[t];
                BIASB[256 + t] = b3[t];
            }
        }
        __syncthreads();

        const int wv   = t >> 6;
        const int lane = t & 63;
        const int nn   = lane & 15;
        const int q    = lane >> 4;

        // ---- hidden layers 1..3 via MFMA (2-pass) ----
        #pragma unroll 1
        for (int l = 0; l < 3; l++) {
            const unsigned short* WpL = wsU + l * 32768;
            f32x4 acc[2][2];
            #pragma unroll
            for (int i = 0; i < 2; i++)
                #pragma unroll
                for (int n = 0; n < 2; n++) {
                    acc[i][n][0] = 0.f; acc[i][n][1] = 0.f;
                    acc[i][n][2] = 0.f; acc[i][n][3] = 0.f;
                }
            #pragma unroll
            for (int ks = 0; ks < 4; ks++) {
                FragU bh[2];
                #pragma unroll
                for (int n = 0; n < 2; n++)
                    bh[n].q = *(const uint4*)(ShU + (n * 16 + nn) * 136 + ks * 32 + q * 8);
                FragU wh[2], wl[2];
                #pragma unroll
                for (int i = 0; i < 2; i++) {
                    const unsigned short* base =
                        WpL + ((((2 * wv + i) * 4 + ks) * 64 + lane) << 3);
                    wh[i].q = *(const uint4*)base;
                    wl[i].q = *(const uint4*)(base + 16384);
                }
                #pragma unroll
                for (int i = 0; i < 2; i++)
                    #pragma unroll
                    for (int n = 0; n < 2; n++) {
                        acc[i][n] = __builtin_amdgcn_mfma_f32_16x16x32_f16(
                            wh[i].b, bh[n].b, acc[i][n], 0, 0, 0);
                        acc[i][n] = __builtin_amdgcn_mfma_f32_16x16x32_f16(
                            wl[i].b, bh[n].b, acc[i][n], 0, 0, 0);
                    }
            }
            __syncthreads();
            #pragma unroll
            for (int i = 0; i < 2; i++) {
                int ubase = (2 * wv + i) * 16 + q * 4;
                F4 bv; bv.v = *(const float4*)&BIASB[l * 128 + ubase];
                #pragma unroll
                for (int n = 0; n < 2; n++) {
                    U2h ph;
                    #pragma unroll
                    for (int r = 0; r < 4; r++)
                        ph.e[r] = (_Float16)fast_tanh(acc[i][n][r] + bv.f[r]);
                    *(uint2*)(ShU + (n * 16 + nn) * 136 + ubase) = ph.d;
                }
            }
            __syncthreads();
        }

        // ---- layer 4: 128 -> 4, k-split 8 ----
        {
            int p2 = t & 31, kg = t >> 5;
            float a0 = 0.f, a1 = 0.f, a2 = 0.f, a3 = 0.f;
            if (kg == 0) { a0 = b4[0]; a1 = b4[1]; a2 = b4[2]; a3 = b4[3]; }
            int abase = p2 * 136 + kg * 16;
            #pragma unroll
            for (int g = 0; g < 4; g++) {
                U2h hh;
                hh.d = *(const uint2*)(ShU + abase + g * 4);
                #pragma unroll
                for (int e = 0; e < 4; e++) {
                    float a = (float)hh.e[e];
                    float4 w = *(const float4*)(W4 + (kg * 16 + g * 4 + e) * 4);
                    a0 += a * w.x; a1 += a * w.y; a2 += a * w.z; a3 += a * w.w;
                }
            }
            *(float4*)&PBf[(kg * 32 + p2) * 4] = make_float4(a0, a1, a2, a3);
        }
        __syncthreads();

        float contrib = 0.f;
        if (t < 32) {
            float o0 = 0.f, o1 = 0.f, o2 = 0.f, o3 = 0.f;
            #pragma unroll
            for (int kg = 0; kg < 8; kg++) {
                float4 pv = *(const float4*)&PBf[(kg * 32 + t) * 4];
                o0 += pv.x; o1 += pv.y; o2 += pv.z; o3 += pv.w;
            }
            float l;
            if (batch == 0) {
                float4 Ui = *(const float4*)(U_inlet + (base_pt + t) * 4);
                float d0 = o0 - Ui.x, d1 = o1 - Ui.y, d2 = o2 - Ui.z, d3 = o3 - Ui.w;
                l = d0 * d0 + d1 * d1 + d2 * d2 + d3 * d3;
            } else if (batch == 3) {
                const float sa = -0.17364817766693033f;  // sin(-pi/18)
                const float ca =  0.9848077530122080f;   // cos(-pi/18)
                float d = -o2 * sa + o3 * ca;
                l = d * d;
            } else {
                l = o3 * o3;
            }
            contrib = 10.0f * l * (1.0f / (float)NBDY);
        }
        if (t < 64) {
            contrib += __shfl_down(contrib, 16);
            contrib += __shfl_down(contrib, 8);
            contrib += __shfl_down(contrib, 4);
            contrib += __shfl_down(contrib, 2);
            contrib += __shfl_down(contrib, 1);
            if (t == 0) atomicAdd(out, contrib);
        }
    }
}

extern "C" void kernel_launch(void* const* d_in, const int* in_sizes, int n_in,
                              void* d_out, int out_size, void* d_ws, size_t ws_size,
                              hipStream_t stream) {
    const float* xt      = (const float*)d_in[0];
    const float* x_inlet = (const float*)d_in[1];
    const float* U_inlet = (const float*)d_in[2];
    const float* x_base  = (const float*)d_in[3];
    const float* x_top   = (const float*)d_in[4];
    const float* x_slip  = (const float*)d_in[5];
    const float* W0 = (const float*)d_in[6];
    const float* b0 = (const float*)d_in[7];
    const float* W1 = (const float*)d_in[8];
    const float* b1 = (const float*)d_in[9];
    const float* W2 = (const float*)d_in[10];
    const float* b2 = (const float*)d_in[11];
    const float* W3 = (const float*)d_in[12];
    const float* b3 = (const float*)d_in[13];
    const float* W4 = (const float*)d_in[14];
    const float* b4 = (const float*)d_in[15];
    const float* V0 = (const float*)d_in[16];
    const float* c0 = (const float*)d_in[17];
    const float* V1 = (const float*)d_in[18];
    const float* c1 = (const float*)d_in[19];
    const float* V2 = (const float*)d_in[20];
    const float* c2 = (const float*)d_in[21];
    float* out = (float*)d_out;
    unsigned short* wsU = (unsigned short*)d_ws;

    pack_w_kernel<<<4, 256, 0, stream>>>(W1, W2, W3, V1, wsU, out);

    fused_kernel<<<PHYS_BLOCKS + BDY_BLOCKS, 256, 0, stream>>>(
        xt, x_inlet, U_inlet, x_base, x_top, x_slip,
        W0, b0, W1, b1, W2, b2, W3, b3, W4, b4,
        V0, c0, V1, c1, V2, c2, wsU, out);
}

// Round 6
// 162.796 us; speedup vs baseline: 2.2666x; 1.0406x over previous
//
#include <hip/hip_runtime.h>

#define NTRAIN 32768
#define NBDY   4096
#define PHYS_BLOCKS (NTRAIN / 16)   // 2048
#define BDY_BLOCKS  512             // 32 pts/block, 128 blocks per batch

typedef _Float16 f16x8 __attribute__((ext_vector_type(8)));
typedef float    f32x4 __attribute__((ext_vector_type(4)));

union FragU { uint4 q; f16x8 b; _Float16 e[8]; };
union F4  { float4 v; float f[4]; };
union U2h { _Float16 e[4]; uint2 d; };
union H2  { _Float16 h[2]; unsigned int u; };

__device__ __forceinline__ float fast_tanh(float z) {
    float e = __expf(2.0f * z);
    return 1.0f - 2.0f / (e + 1.0f);
}

// ---------------------------------------------------------------------------
// Pack W1..W3 (fp16 hi+lo) and V1 (fp16) into MFMA A-fragment order.
// Fragment ushort offset for element (k,n):
//   off(k,n) = (((n>>4)*KS + (k>>5))*64 + ((k>>3)&3)*16 + (n&15))*8 + (k&7)
// (KS=4 for 128-k W, KS=2 for 64-k V1). Even-k pairs are consecutive
// ushorts -> one uint write. READS are row-major coalesced (lane n ->
// consecutive dwords); WRITES are scattered 4B (posted, no stall).
// hi at wsU + l*32768, lo at +16384 (ushorts). V1-hi at wsU + 98304.
// ---------------------------------------------------------------------------
__global__ __launch_bounds__(256) void pack_w_kernel(
    const float* __restrict__ W1, const float* __restrict__ W2,
    const float* __restrict__ W3, const float* __restrict__ V1,
    unsigned short* __restrict__ wsU, float* __restrict__ out)
{
    int b = blockIdx.x;
    if (b < 24) {
        int mat = b >> 3, rb = b & 7;          // 16 rows per block
        const float* W = (mat == 0) ? W1 : (mat == 1) ? W2 : W3;
        unsigned int* hiU = (unsigned int*)(wsU + mat * 32768);
        unsigned int* loU = hiU + 8192;
        int n   = threadIdx.x & 127;
        int pr0 = threadIdx.x >> 7;
        #pragma unroll
        for (int it = 0; it < 4; it++) {
            int pr = pr0 + 2 * it;             // pair 0..7
            int k  = rb * 16 + pr * 2;
            float v0 = W[k * 128 + n];
            float v1 = W[(k + 1) * 128 + n];
            H2 hh, ll;
            hh.h[0] = (_Float16)v0;
            hh.h[1] = (_Float16)v1;
            ll.h[0] = (_Float16)(v0 - (float)hh.h[0]);
            ll.h[1] = (_Float16)(v1 - (float)hh.h[1]);
            int base = ((n >> 4) * 4 + (k >> 5)) * 64 + ((k >> 3) & 3) * 16 + (n & 15);
            int uoff = base * 4 + ((k & 7) >> 1);
            hiU[uoff] = hh.u;
            loU[uoff] = ll.u;
        }
    } else {
        unsigned int* hiU = (unsigned int*)(wsU + 98304);
        int n   = threadIdx.x & 63;
        int pr0 = threadIdx.x >> 6;
        #pragma unroll
        for (int it = 0; it < 8; it++) {
            int pr = pr0 + 4 * it;             // pair 0..31
            int k  = pr * 2;
            float v0 = V1[k * 64 + n];
            float v1 = V1[(k + 1) * 64 + n];
            H2 hh;
            hh.h[0] = (_Float16)v0;
            hh.h[1] = (_Float16)v1;
            int base = ((n >> 4) * 2 + (k >> 5)) * 64 + ((k >> 3) & 3) * 16 + (n & 15);
            hiU[base * 4 + ((k & 7) >> 1)] = hh.u;
        }
        if (threadIdx.x == 0) out[0] = 0.f;
    }
}

// ---------------------------------------------------------------------------
// Fused kernel. Blocks [0,2048): physics (16 pts, 4 AD streams:
// 0=value 1=d/dx 2=d/dy 3=Laplacian). Blocks [2048,2560): boundary.
//
// Laplacian propagation: h=tanh(z): h_lap = s2*z_lap + m2*(zx^2+zy^2),
// s2=1-t^2, m2=-2*t*s2 -> one stream replaces dxx+dyy (residual only needs
// Laplacians of the outputs).
// fp16 2-pass weight emulation: acc = Wh*a + Wl*a (W^T as A-operand from
// packed global); activations single fp16 plane in LDS (64 rows x 136).
// D layout: lane = (point nn, unit-quad q): lane-local transform, b64 stores.
// ---------------------------------------------------------------------------
__global__ __launch_bounds__(256, 7) void fused_kernel(
    const float* __restrict__ xt,
    const float* __restrict__ x_inlet, const float* __restrict__ U_inlet,
    const float* __restrict__ x_base,  const float* __restrict__ x_top,
    const float* __restrict__ x_slip,
    const float* __restrict__ W0, const float* __restrict__ b0,
    const float* __restrict__ W1, const float* __restrict__ b1,
    const float* __restrict__ W2, const float* __restrict__ b2,
    const float* __restrict__ W3, const float* __restrict__ b3,
    const float* __restrict__ W4, const float* __restrict__ b4,
    const float* __restrict__ V0, const float* __restrict__ c0,
    const float* __restrict__ V1, const float* __restrict__ c1,
    const float* __restrict__ V2, const float* __restrict__ c2,
    const unsigned short* __restrict__ wsU,
    float* __restrict__ out)
{
    __shared__ float SM[5136];   // 20544 B -> 7 blocks/CU
    const int t = threadIdx.x;

    if (blockIdx.x < PHYS_BLOCKS) {
        // =================== PHYSICS PATH ===================
        unsigned short* AhU = (unsigned short*)SM;   // 64 rows x 136 ushorts
        float* PART  = SM + 4352;   // 128 x 4 floats (layer-4 partials)
        float* BIASF = SM + 4352;   // b1|b2|b3 (384 floats), dead before L4
        float* OUTF  = SM + 4864;   // 64 x 4
        float* MUV   = SM + 5120;   // 16
        // mu MLP scratch overlaps A region (consumed before layer 0 writes)
        unsigned short* MUhU  = AhU;          // 16 x 72
        unsigned short* MU2hU = AhU + 1152;   // 16 x 72

        const int p = t >> 4;   // point 0..15
        const int c = t & 15;

        const int ptIdx = blockIdx.x * 16 + p;
        const float2 xy = *(const float2*)(xt + ptIdx * 2);
        const float x = xy.x, y = xy.y;

        // stage hidden-layer biases (PART region, consumed before L4)
        if (t < 128) {
            BIASF[t]       = b1[t];
            BIASF[128 + t] = b2[t];
            BIASF[256 + t] = b3[t];
        }

        // ---------------- mu MLP layer 1: 2 -> 64 --------------------------
        {
            F4 va, vb, cc;
            va.v = *(const float4*)(V0 + c * 4);
            vb.v = *(const float4*)(V0 + 64 + c * 4);
            cc.v = *(const float4*)(c0 + c * 4);
            U2h ph;
            #pragma unroll
            for (int i = 0; i < 4; i++)
                ph.e[i] = (_Float16)fast_tanh(x * va.f[i] + y * vb.f[i] + cc.f[i]);
            *(uint2*)(MUhU + p * 72 + c * 4) = ph.d;
        }
        __syncthreads();

        const int wv   = t >> 6;
        const int lane = t & 63;
        const int nn   = lane & 15;
        const int q    = lane >> 4;

        // ---------------- mu MLP layer 2: 64 -> 64 via MFMA (1-pass) -------
        {
            f32x4 macc = {0.f, 0.f, 0.f, 0.f};
            #pragma unroll
            for (int ks = 0; ks < 2; ks++) {
                FragU mh, vh;
                mh.q = *(const uint4*)(MUhU + nn * 72 + ks * 32 + q * 8);
                vh.q = *(const uint4*)(wsU + 98304 + (((wv * 2 + ks) * 64 + lane) << 3));
                macc = __builtin_amdgcn_mfma_f32_16x16x32_f16(vh.b, mh.b, macc, 0, 0, 0);
            }
            int u2base = wv * 16 + q * 4;
            F4 cv; cv.v = *(const float4*)(c1 + u2base);
            U2h ph;
            #pragma unroll
            for (int r = 0; r < 4; r++)
                ph.e[r] = (_Float16)fast_tanh(macc[r] + cv.f[r]);
            *(uint2*)(MU2hU + nn * 72 + u2base) = ph.d;
        }
        __syncthreads();

        // ---------------- mu MLP layer 3: 64 -> 1 (one wave) ---------------
        if (t < 64) {
            int pt = t & 15, kg = t >> 4;
            float partial = 0.f;
            int base = pt * 72 + kg * 16;
            #pragma unroll
            for (int g = 0; g < 4; g++) {
                U2h hh;
                hh.d = *(const uint2*)(MU2hU + base + g * 4);
                F4 w; w.v = *(const float4*)(V2 + kg * 16 + g * 4);
                #pragma unroll
                for (int e = 0; e < 4; e++)
                    partial += (float)hh.e[e] * w.f[e];
            }
            partial += __shfl_down(partial, 32);
            partial += __shfl_down(partial, 16);
            if (t < 16) {
                float s = partial + c2[0];
                MUV[t] = 0.01f * s * s;
            }
        }
        __syncthreads();

        // ---------------- layer 0: 2 -> 128, 4 streams ---------------------
        {
            float vals[4][8];
            #pragma unroll
            for (int j = 0; j < 8; j++) {
                int u = c * 8 + j;
                float w0 = W0[u], w1 = W0[128 + u];
                float zv = x * w0 + y * w1 + b0[u];
                float tt = fast_tanh(zv);
                float s2 = 1.f - tt * tt;
                float m2 = -2.f * tt * s2;
                vals[0][j] = tt;
                vals[1][j] = s2 * w0;
                vals[2][j] = s2 * w1;
                vals[3][j] = m2 * (w0 * w0 + w1 * w1);  // z_lap = 0 at layer 0
            }
            #pragma unroll
            for (int s = 0; s < 4; s++) {
                FragU fh;
                #pragma unroll
                for (int j = 0; j < 8; j++) fh.e[j] = (_Float16)vals[s][j];
                *(uint4*)(AhU + (s * 16 + p) * 136 + c * 8) = fh.q;
            }
        }
        __syncthreads();

        // ---------------- hidden layers 1..3 via MFMA (W hi/lo 2-pass) -----
        #pragma unroll 1
        for (int l = 0; l < 3; l++) {
            const unsigned short* WpL = wsU + l * 32768;
            f32x4 acc[2][4];
            #pragma unroll
            for (int i = 0; i < 2; i++)
                #pragma unroll
                for (int s = 0; s < 4; s++) {
                    acc[i][s][0] = 0.f; acc[i][s][1] = 0.f;
                    acc[i][s][2] = 0.f; acc[i][s][3] = 0.f;
                }
            #pragma unroll
            for (int ks = 0; ks < 4; ks++) {
                FragU bh[4];
                #pragma unroll
                for (int s = 0; s < 4; s++)
                    bh[s].q = *(const uint4*)(AhU + (s * 16 + nn) * 136 + ks * 32 + q * 8);
                FragU wh[2], wl[2];
                #pragma unroll
                for (int i = 0; i < 2; i++) {
                    const unsigned short* base =
                        WpL + ((((2 * wv + i) * 4 + ks) * 64 + lane) << 3);
                    wh[i].q = *(const uint4*)base;
                    wl[i].q = *(const uint4*)(base + 16384);
                }
                #pragma unroll
                for (int i = 0; i < 2; i++)
                    #pragma unroll
                    for (int s = 0; s < 4; s++) {
                        acc[i][s] = __builtin_amdgcn_mfma_f32_16x16x32_f16(
                            wh[i].b, bh[s].b, acc[i][s], 0, 0, 0);
                        acc[i][s] = __builtin_amdgcn_mfma_f32_16x16x32_f16(
                            wl[i].b, bh[s].b, acc[i][s], 0, 0, 0);
                    }
            }
            __syncthreads();   // all A reads done before overwrite
            #pragma unroll
            for (int i = 0; i < 2; i++) {
                int ubase = (2 * wv + i) * 16 + q * 4;
                F4 bv; bv.v = *(const float4*)&BIASF[l * 128 + ubase];
                float vals[4][4];
                #pragma unroll
                for (int r = 0; r < 4; r++) {
                    float z  = acc[i][0][r] + bv.f[r];
                    float zx = acc[i][1][r], zy = acc[i][2][r];
                    float zl = acc[i][3][r];
                    float tt = fast_tanh(z);
                    float s2 = 1.f - tt * tt;
                    float m2 = -2.f * tt * s2;
                    vals[0][r] = tt;
                    vals[1][r] = s2 * zx;
                    vals[2][r] = s2 * zy;
                    vals[3][r] = s2 * zl + m2 * (zx * zx + zy * zy);
                }
                #pragma unroll
                for (int s = 0; s < 4; s++) {
                    U2h ph;
                    #pragma unroll
                    for (int r = 0; r < 4; r++) ph.e[r] = (_Float16)vals[s][r];
                    *(uint2*)(AhU + (s * 16 + nn) * 136 + ubase) = ph.d;
                }
            }
            __syncthreads();
        }

        // ---------------- layer 4: 128 -> 4 (linear), k-split 2 ------------
        if (t < 128) {
            int r    = t >> 1;   // row 0..63 = s*16 + p
            int half = t & 1;
            float a0 = 0.f, a1 = 0.f, a2 = 0.f, a3 = 0.f;
            if (half == 0 && r < 16) { a0 = b4[0]; a1 = b4[1]; a2 = b4[2]; a3 = b4[3]; }
            const int abase = r * 136 + half * 64;
            const float* W4h = W4 + half * 256;
            #pragma unroll
            for (int k0 = 0; k0 < 64; k0 += 8) {
                FragU qh;
                qh.q = *(const uint4*)(AhU + abase + k0);
                #pragma unroll
                for (int j = 0; j < 8; j++) {
                    float a = (float)qh.e[j];
                    float4 w = *(const float4*)(W4h + (k0 + j) * 4);
                    a0 += a * w.x; a1 += a * w.y; a2 += a * w.z; a3 += a * w.w;
                }
            }
            *(float4*)&PART[t * 4] = make_float4(a0, a1, a2, a3);
        }
        __syncthreads();
        if (t < 64) {
            float4 u0 = *(float4*)&PART[(2 * t) * 4];
            float4 u1 = *(float4*)&PART[(2 * t + 1) * 4];
            *(float4*)&OUTF[t * 4] =
                make_float4(u0.x + u1.x, u0.y + u1.y, u0.z + u1.z, u0.w + u1.w);
        }
        __syncthreads();

        // ---------------- per-point residual + reduction -------------------
        float contrib = 0.f;
        if (t < 16) {
            const int pp = t;
            const float* V   = &OUTF[(0  + pp) * 4];
            const float* DX  = &OUTF[(16 + pp) * 4];
            const float* DY  = &OUTF[(32 + pp) * 4];
            const float* LAP = &OUTF[(48 + pp) * 4];
            float r = V[0],  P = V[1],  u = V[2],  v = V[3];
            float rx = DX[0], Px = DX[1], ux = DX[2], vx = DX[3];
            float ry = DY[0], Py = DY[1], uy = DY[2], vy = DY[3];
            float rl = LAP[0], Pl = LAP[1], ul = LAP[2], vl = LAP[3];
            const float GI = 2.5f;  // 1/(gamma-1)

            float q2 = u * u + v * v;
            float E  = P * GI + 0.5f * r * q2;
            float Ex = Px * GI + 0.5f * rx * q2 + r * (u * ux + v * vx);
            float Ey = Py * GI + 0.5f * ry * q2 + r * (u * uy + v * vy);
            float EpP = E + P;

            float f1x = rx * u + r * ux;
            float f2x = rx * u * u + 2.f * r * u * ux + Px;
            float f3x = rx * u * v + r * ux * v + r * u * vx;
            float f4x = ux * EpP + u * (Ex + Px);

            float g1y = ry * v + r * vy;
            float g2y = ry * u * v + r * uy * v + r * u * vy;
            float g3y = ry * v * v + 2.f * r * v * vy + Py;
            float g4y = vy * EpP + v * (Ey + Py);

            float qx  = 2.f * (u * ux + v * vx);
            float qy  = 2.f * (u * uy + v * vy);
            float ql  = 2.f * (ux * ux + uy * uy + vx * vx + vy * vy)
                      + 2.f * (u * ul + v * vl);

            float U1s = rl;
            float U2s = rl * u + 2.f * (rx * ux + ry * uy) + r * ul;
            float U3s = rl * v + 2.f * (rx * vx + ry * vy) + r * vl;
            float U4s = Pl * GI
                      + 0.5f * (rl * q2 + 2.f * (rx * qx + ry * qy) + r * ql);

            float mu = MUV[pp];
            float r1 = f1x + g1y - mu * U1s;
            float r2 = f2x + g2y - mu * U2s;
            float r3 = f3x + g3y - mu * U3s;
            float r4 = f4x + g4y - mu * U4s;

            contrib = (r1 * r1 + r2 * r2 + r3 * r3 + r4 * r4 + 0.1f * mu * mu)
                      * (1.0f / (float)NTRAIN);
        }
        if (t < 64) {
            contrib += __shfl_down(contrib, 32);
            contrib += __shfl_down(contrib, 16);
            contrib += __shfl_down(contrib, 8);
            contrib += __shfl_down(contrib, 4);
            contrib += __shfl_down(contrib, 2);
            contrib += __shfl_down(contrib, 1);
            if (t == 0) atomicAdd(out, contrib);
        }
    } else {
        // =================== BOUNDARY PATH (MFMA, 32 pts/block) ============
        unsigned short* ShU = (unsigned short*)SM;   // 32 x 136
        float* PBf   = SM + 2176;   // 8 x 32 x 4 floats
        float* BIASB = SM + 3200;   // 384 floats

        const int bb    = blockIdx.x - PHYS_BLOCKS;
        const int batch = bb >> 7;  // 0..3 (128 blocks each)
        const int lb    = bb & 127;
        const float* xs = (batch == 0) ? x_inlet
                        : (batch == 1) ? x_base
                        : (batch == 2) ? x_top : x_slip;
        const int base_pt = lb * 32;

        // ---- layer 0: 2 -> 128 + bias staging ----
        {
            int p2 = t & 31, ug = t >> 5;
            float2 xy = *(const float2*)(xs + (base_pt + p2) * 2);
            float x = xy.x, y = xy.y;
            #pragma unroll
            for (int g = 0; g < 4; g++) {
                int u0 = ug * 16 + g * 4;
                F4 wa, wb, bbv;
                wa.v  = *(const float4*)(W0 + u0);
                wb.v  = *(const float4*)(W0 + 128 + u0);
                bbv.v = *(const float4*)(b0 + u0);
                U2h ph;
                #pragma unroll
                for (int e = 0; e < 4; e++)
                    ph.e[e] = (_Float16)fast_tanh(x * wa.f[e] + y * wb.f[e] + bbv.f[e]);
                *(uint2*)(ShU + p2 * 136 + u0) = ph.d;
            }
            if (t < 128) {
                BIASB[t]       = b1[t];
                BIASB[128 + t] = b2[t];
                BIASB[256 + t] = b3[t];
            }
        }
        __syncthreads();

        const int wv   = t >> 6;
        const int lane = t & 63;
        const int nn   = lane & 15;
        const int q    = lane >> 4;

        // ---- hidden layers 1..3 via MFMA (2-pass) ----
        #pragma unroll 1
        for (int l = 0; l < 3; l++) {
            const unsigned short* WpL = wsU + l * 32768;
            f32x4 acc[2][2];
            #pragma unroll
            for (int i = 0; i < 2; i++)
                #pragma unroll
                for (int n = 0; n < 2; n++) {
                    acc[i][n][0] = 0.f; acc[i][n][1] = 0.f;
                    acc[i][n][2] = 0.f; acc[i][n][3] = 0.f;
                }
            #pragma unroll
            for (int ks = 0; ks < 4; ks++) {
                FragU bh[2];
                #pragma unroll
                for (int n = 0; n < 2; n++)
                    bh[n].q = *(const uint4*)(ShU + (n * 16 + nn) * 136 + ks * 32 + q * 8);
                FragU wh[2], wl[2];
                #pragma unroll
                for (int i = 0; i < 2; i++) {
                    const unsigned short* base =
                        WpL + ((((2 * wv + i) * 4 + ks) * 64 + lane) << 3);
                    wh[i].q = *(const uint4*)base;
                    wl[i].q = *(const uint4*)(base + 16384);
                }
                #pragma unroll
                for (int i = 0; i < 2; i++)
                    #pragma unroll
                    for (int n = 0; n < 2; n++) {
                        acc[i][n] = __builtin_amdgcn_mfma_f32_16x16x32_f16(
                            wh[i].b, bh[n].b, acc[i][n], 0, 0, 0);
                        acc[i][n] = __builtin_amdgcn_mfma_f32_16x16x32_f16(
                            wl[i].b, bh[n].b, acc[i][n], 0, 0, 0);
                    }
            }
            __syncthreads();
            #pragma unroll
            for (int i = 0; i < 2; i++) {
                int ubase = (2 * wv + i) * 16 + q * 4;
                F4 bv; bv.v = *(const float4*)&BIASB[l * 128 + ubase];
                #pragma unroll
                for (int n = 0; n < 2; n++) {
                    U2h ph;
                    #pragma unroll
                    for (int r = 0; r < 4; r++)
                        ph.e[r] = (_Float16)fast_tanh(acc[i][n][r] + bv.f[r]);
                    *(uint2*)(ShU + (n * 16 + nn) * 136 + ubase) = ph.d;
                }
            }
            __syncthreads();
        }

        // ---- layer 4: 128 -> 4, k-split 8 ----
        {
            int p2 = t & 31, kg = t >> 5;
            float a0 = 0.f, a1 = 0.f, a2 = 0.f, a3 = 0.f;
            if (kg == 0) { a0 = b4[0]; a1 = b4[1]; a2 = b4[2]; a3 = b4[3]; }
            int abase = p2 * 136 + kg * 16;
            #pragma unroll
            for (int g = 0; g < 4; g++) {
                U2h hh;
                hh.d = *(const uint2*)(ShU + abase + g * 4);
                #pragma unroll
                for (int e = 0; e < 4; e++) {
                    float a = (float)hh.e[e];
                    float4 w = *(const float4*)(W4 + (kg * 16 + g * 4 + e) * 4);
                    a0 += a * w.x; a1 += a * w.y; a2 += a * w.z; a3 += a * w.w;
                }
            }
            *(float4*)&PBf[(kg * 32 + p2) * 4] = make_float4(a0, a1, a2, a3);
        }
        __syncthreads();

        float contrib = 0.f;
        if (t < 32) {
            float o0 = 0.f, o1 = 0.f, o2 = 0.f, o3 = 0.f;
            #pragma unroll
            for (int kg = 0; kg < 8; kg++) {
                float4 pv = *(const float4*)&PBf[(kg * 32 + t) * 4];
                o0 += pv.x; o1 += pv.y; o2 += pv.z; o3 += pv.w;
            }
            float l;
            if (batch == 0) {
                float4 Ui = *(const float4*)(U_inlet + (base_pt + t) * 4);
                float d0 = o0 - Ui.x, d1 = o1 - Ui.y, d2 = o2 - Ui.z, d3 = o3 - Ui.w;
                l = d0 * d0 + d1 * d1 + d2 * d2 + d3 * d3;
            } else if (batch == 3) {
                const float sa = -0.17364817766693033f;  // sin(-pi/18)
                const float ca =  0.9848077530122080f;   // cos(-pi/18)
                float d = -o2 * sa + o3 * ca;
                l = d * d;
            } else {
                l = o3 * o3;
            }
            contrib = 10.0f * l * (1.0f / (float)NBDY);
        }
        if (t < 64) {
            contrib += __shfl_down(contrib, 16);
            contrib += __shfl_down(contrib, 8);
            contrib += __shfl_down(contrib, 4);
            contrib += __shfl_down(contrib, 2);
            contrib += __shfl_down(contrib, 1);
            if (t == 0) atomicAdd(out, contrib);
        }
    }
}

extern "C" void kernel_launch(void* const* d_in, const int* in_sizes, int n_in,
                              void* d_out, int out_size, void* d_ws, size_t ws_size,
                              hipStream_t stream) {
    const float* xt      = (const float*)d_in[0];
    const float* x_inlet = (const float*)d_in[1];
    const float* U_inlet = (const float*)d_in[2];
    const float* x_base  = (const float*)d_in[3];
    const float* x_top   = (const float*)d_in[4];
    const float* x_slip  = (const float*)d_in[5];
    const float* W0 = (const float*)d_in[6];
    const float* b0 = (const float*)d_in[7];
    const float* W1 = (const float*)d_in[8];
    const float* b1 = (const float*)d_in[9];
    const float* W2 = (const float*)d_in[10];
    const float* b2 = (const float*)d_in[11];
    const float* W3 = (const float*)d_in[12];
    const float* b3 = (const float*)d_in[13];
    const float* W4 = (const float*)d_in[14];
    const float* b4 = (const float*)d_in[15];
    const float* V0 = (const float*)d_in[16];
    const float* c0 = (const float*)d_in[17];
    const float* V1 = (const float*)d_in[18];
    const float* c1 = (const float*)d_in[19];
    const float* V2 = (const float*)d_in[20];
    const float* c2 = (const float*)d_in[21];
    float* out = (float*)d_out;
    unsigned short* wsU = (unsigned short*)d_ws;

    pack_w_kernel<<<25, 256, 0, stream>>>(W1, W2, W3, V1, wsU, out);

    fused_kernel<<<PHYS_BLOCKS + BDY_BLOCKS, 256, 0, stream>>>(
        xt, x_inlet, U_inlet, x_base, x_top, x_slip,
        W0, b0, W1, b1, W2, b2, W3, b3, W4, b4,
        V0, c0, V1, c1, V2, c2, wsU, out);
}